// Round 2
// baseline (1005.638 us; speedup 1.0000x reference)
//
#include <hip/hip_runtime.h>
#include <hip/hip_bf16.h>
#include <stdint.h>

// GCN forward, collapsed to scalar form (W1:[1,16], W2:[16,1] are rank-1):
//   deg pass  : deg[dst]++                       (reads dst: 25.6 MB)
//   node1     : dinv[n], y[n]=dropout1(x[n])*dinv[n], out[n]=b2
//   scatter1  : s[dst] += y[src]                 (reads src+dst: 51.2 MB)
//   node2     : z2[n] = dinv[n] * sum_c W2[c]*dropout2(relu(W1[c]*s[n]*dinv[n]+b1[c]))
//   scatter2  : out[dst] += z2[src]*dinv[dst]    (reads src+dst: 51.2 MB)
//
// Dropout masks reproduce JAX threefry2x32, *partitionable* scheme
// (default since JAX 0.4.30):
//   split:  k_i = E(key, (0, i)) using BOTH output words  (foldlike split)
//   bits for flat index j (32-bit): counts = (hi=0, lo=j) of 64-bit iota,
//       (o0, o1) = E(k, (0, j));  bits = o0 ^ o1          // <-- XOR, the R1 fix
//   u = bitcast((bits>>9)|0x3f800000) - 1.0f ;  keep iff u < 0.4f
// FALLBACK if absmax ~0.14 again: pre-0.4.30 original scheme =
//   split: x0=[0,1], x1=[2,3] -> k1=(o0(0,2), o0(1,3)), k2=(o1(0,2), o1(1,3));
//   bits[i] (size n, h=ceil(n/2)): i<h ? o0 of E(k,(i,i+h)) : o1 of E(k,(i-h,i)).

#define KEEP_P 0.4f

__host__ __device__ inline unsigned rotl32(unsigned v, int s) {
  return (v << s) | (v >> (32 - s));
}

__host__ __device__ inline void threefry2x32(unsigned key0, unsigned key1,
                                             unsigned x0, unsigned x1,
                                             unsigned& o0, unsigned& o1) {
  unsigned ks0 = key0, ks1 = key1, ks2 = key0 ^ key1 ^ 0x1BD11BDAu;
  unsigned v0 = x0 + ks0, v1 = x1 + ks1;
#define TF_R(r) { v0 += v1; v1 = rotl32(v1, r); v1 ^= v0; }
  TF_R(13) TF_R(15) TF_R(26) TF_R(6)
  v0 += ks1; v1 += ks2 + 1u;
  TF_R(17) TF_R(29) TF_R(16) TF_R(24)
  v0 += ks2; v1 += ks0 + 2u;
  TF_R(13) TF_R(15) TF_R(26) TF_R(6)
  v0 += ks0; v1 += ks1 + 3u;
  TF_R(17) TF_R(29) TF_R(16) TF_R(24)
  v0 += ks1; v1 += ks2 + 4u;
  TF_R(13) TF_R(15) TF_R(26) TF_R(6)
  v0 += ks2; v1 += ks0 + 5u;
#undef TF_R
  o0 = v0; o1 = v1;
}

__device__ inline float u01_from_bits(unsigned bits) {
  return __uint_as_float((bits >> 9) | 0x3f800000u) - 1.0f;
}

// ---- K1: in-degree ---------------------------------------------------------
__global__ __launch_bounds__(256) void k_deg(const int* __restrict__ dst,
                                             int* __restrict__ deg,
                                             int e4, int E) {
  int i = blockIdx.x * blockDim.x + threadIdx.x;
  if (i < e4) {
    int4 d = reinterpret_cast<const int4*>(dst)[i];
    atomicAdd(&deg[d.x], 1);
    atomicAdd(&deg[d.y], 1);
    atomicAdd(&deg[d.z], 1);
    atomicAdd(&deg[d.w], 1);
  }
  if (i == 0) {  // tail (E not multiple of 4) — no-op for E=6.4M
    for (int t = e4 * 4; t < E; ++t) atomicAdd(&deg[dst[t]], 1);
  }
}

// ---- K2: per-node: dinv, dropout1, y, out=b2 -------------------------------
__global__ __launch_bounds__(256) void k_node1(
    const float* __restrict__ x, const int* __restrict__ deg,
    float* __restrict__ dinv, float* __restrict__ y, float* __restrict__ out,
    const float* __restrict__ b2, int n, unsigned k1a, unsigned k1b) {
  int i = blockIdx.x * blockDim.x + threadIdx.x;
  if (i >= n) return;
  int d = deg[i];
  float di = (d > 0) ? (1.0f / sqrtf((float)d)) : 0.0f;
  dinv[i] = di;
  unsigned o0, o1;
  threefry2x32(k1a, k1b, 0u, (unsigned)i, o0, o1);
  float u = u01_from_bits(o0 ^ o1);   // partitionable 32-bit bits = out0 ^ out1
  float xd = (u < KEEP_P) ? (x[i] / KEEP_P) : 0.0f;
  y[i] = xd * di;
  out[i] = b2[0];
}

// ---- K3: scatter layer 1: s[dst] += y[src] ---------------------------------
__global__ __launch_bounds__(256) void k_scat1(
    const int* __restrict__ src, const int* __restrict__ dst,
    const float* __restrict__ y, float* __restrict__ s, int e4, int E) {
  int i = blockIdx.x * blockDim.x + threadIdx.x;
  if (i < e4) {
    int4 sv = reinterpret_cast<const int4*>(src)[i];
    int4 dv = reinterpret_cast<const int4*>(dst)[i];
    atomicAdd(&s[dv.x], y[sv.x]);
    atomicAdd(&s[dv.y], y[sv.y]);
    atomicAdd(&s[dv.z], y[sv.z]);
    atomicAdd(&s[dv.w], y[sv.w]);
  }
  if (i == 0) {
    for (int t = e4 * 4; t < E; ++t) atomicAdd(&s[dst[t]], y[src[t]]);
  }
}

// ---- K4: per-node: layer1 epilogue + relu + dropout2 + W2 dot --------------
__global__ __launch_bounds__(256) void k_node2(
    const float* __restrict__ s, const float* __restrict__ dinv,
    const float* __restrict__ W1, const float* __restrict__ b1,
    const float* __restrict__ W2, float* __restrict__ z2, int n,
    unsigned k2a, unsigned k2b) {
  int i = blockIdx.x * blockDim.x + threadIdx.x;
  if (i >= n) return;
  float t = s[i] * dinv[i];
  float z = 0.0f;
  unsigned base = (unsigned)i * 16u;
#pragma unroll
  for (int c = 0; c < 16; ++c) {
    float h = W1[c] * t + b1[c];
    h = fmaxf(h, 0.0f);
    unsigned o0, o1;
    threefry2x32(k2a, k2b, 0u, base + (unsigned)c, o0, o1);
    float u = u01_from_bits(o0 ^ o1); // partitionable 32-bit bits = out0 ^ out1
    float hd = (u < KEEP_P) ? (h / KEEP_P) : 0.0f;
    z += hd * W2[c];
  }
  z2[i] = z * dinv[i];
}

// ---- K5: scatter layer 2: out[dst] += z2[src]*dinv[dst] --------------------
__global__ __launch_bounds__(256) void k_scat2(
    const int* __restrict__ src, const int* __restrict__ dst,
    const float* __restrict__ z2, const float* __restrict__ dinv,
    float* __restrict__ out, int e4, int E) {
  int i = blockIdx.x * blockDim.x + threadIdx.x;
  if (i < e4) {
    int4 sv = reinterpret_cast<const int4*>(src)[i];
    int4 dv = reinterpret_cast<const int4*>(dst)[i];
    atomicAdd(&out[dv.x], z2[sv.x] * dinv[dv.x]);
    atomicAdd(&out[dv.y], z2[sv.y] * dinv[dv.y]);
    atomicAdd(&out[dv.z], z2[sv.z] * dinv[dv.z]);
    atomicAdd(&out[dv.w], z2[sv.w] * dinv[dv.w]);
  }
  if (i == 0) {
    for (int t = e4 * 4; t < E; ++t)
      atomicAdd(&out[dst[t]], z2[src[t]] * dinv[dst[t]]);
  }
}

extern "C" void kernel_launch(void* const* d_in, const int* in_sizes, int n_in,
                              void* d_out, int out_size, void* d_ws, size_t ws_size,
                              hipStream_t stream) {
  const float* x  = (const float*)d_in[0];
  const int* edge = (const int*)d_in[1];   // [2, E] int32 (harness canonicalizes int64)
  const float* W1 = (const float*)d_in[2]; // [1,16]
  const float* b1 = (const float*)d_in[3]; // [16]
  const float* W2 = (const float*)d_in[4]; // [16,1]
  const float* b2 = (const float*)d_in[5]; // [1]
  float* out = (float*)d_out;              // [N,1] f32

  const int N = in_sizes[0];
  const int E = in_sizes[1] / 2;
  const int* src = edge;
  const int* dst = edge + E;

  // Workspace layout (all 4B elems), NP = N padded to 256
  const int NP = (N + 255) & ~255;
  int*   deg  = (int*)d_ws;
  float* s    = (float*)d_ws + 1 * NP;
  float* dinv = (float*)d_ws + 2 * NP;
  float* y    = (float*)d_ws + 3 * NP;
  float* z2   = (float*)d_ws + 4 * NP;

  // Derive dropout keys on host: foldlike split(key(42)), both output words.
  unsigned k1a, k1b, k2a, k2b;
  threefry2x32(0u, 42u, 0u, 0u, k1a, k1b);
  threefry2x32(0u, 42u, 0u, 1u, k2a, k2b);

  // Zero deg + s (ws is poisoned 0xAA before every call)
  hipMemsetAsync(d_ws, 0, (size_t)2 * NP * sizeof(int), stream);

  const int B = 256;
  const int e4 = E >> 2;
  const int gE = (e4 + B - 1) / B;
  const int gN = (N + B - 1) / B;

  k_deg  <<<gE, B, 0, stream>>>(dst, deg, e4, E);
  k_node1<<<gN, B, 0, stream>>>(x, deg, dinv, y, out, b2, N, k1a, k1b);
  k_scat1<<<gE, B, 0, stream>>>(src, dst, y, s, e4, E);
  k_node2<<<gN, B, 0, stream>>>(s, dinv, W1, b1, W2, z2, N, k2a, k2b);
  k_scat2<<<gE, B, 0, stream>>>(src, dst, z2, dinv, out, e4, E);
}

// Round 3
// 964.051 us; speedup vs baseline: 1.0431x; 1.0431x over previous
//
#include <hip/hip_runtime.h>
#include <hip/hip_bf16.h>
#include <stdint.h>

// GCN forward, collapsed to scalar form (W1:[1,16], W2:[16,1] are rank-1).
// R3 change: per-XCD privatized scatter accumulators. R2 showed each fp32
// atomic to the shared 400 KB accumulator cost a 32 B fabric write
// (WRITE_SIZE = E*32B = 200 MB, 8.7% HBM peak, VALUBusy 0.5%): cross-XCD
// line ping-pong through the coherence point. Each XCD now atomics into its
// own copy (xcc = s_getreg(HW_REG_XCC_ID), HW-verified gfx950); lines stay
// exclusive in local L2. Node kernels reduce the 8 copies and re-zero them
// for the next scatter phase, so one 8*NP region serves deg/s/out phases.
// dinv[dst] of layer 2 is folded into the final combine (removes a gather).

#define KEEP_P 0.4f
#define COPIES 8

__device__ inline unsigned xcc_id() {
  unsigned x;
  asm volatile("s_getreg_b32 %0, hwreg(HW_REG_XCC_ID)" : "=s"(x));
  return x & 7u;
}

__host__ __device__ inline unsigned rotl32(unsigned v, int s) {
  return (v << s) | (v >> (32 - s));
}

__host__ __device__ inline void threefry2x32(unsigned key0, unsigned key1,
                                             unsigned x0, unsigned x1,
                                             unsigned& o0, unsigned& o1) {
  unsigned ks0 = key0, ks1 = key1, ks2 = key0 ^ key1 ^ 0x1BD11BDAu;
  unsigned v0 = x0 + ks0, v1 = x1 + ks1;
#define TF_R(r) { v0 += v1; v1 = rotl32(v1, r); v1 ^= v0; }
  TF_R(13) TF_R(15) TF_R(26) TF_R(6)
  v0 += ks1; v1 += ks2 + 1u;
  TF_R(17) TF_R(29) TF_R(16) TF_R(24)
  v0 += ks2; v1 += ks0 + 2u;
  TF_R(13) TF_R(15) TF_R(26) TF_R(6)
  v0 += ks0; v1 += ks1 + 3u;
  TF_R(17) TF_R(29) TF_R(16) TF_R(24)
  v0 += ks1; v1 += ks2 + 4u;
  TF_R(13) TF_R(15) TF_R(26) TF_R(6)
  v0 += ks2; v1 += ks0 + 5u;
#undef TF_R
  o0 = v0; o1 = v1;
}

__device__ inline float u01_from_bits(unsigned bits) {
  return __uint_as_float((bits >> 9) | 0x3f800000u) - 1.0f;
}

// ---- K1: in-degree into per-XCD private copies -----------------------------
__global__ __launch_bounds__(256) void k_deg(const int* __restrict__ dst,
                                             int* __restrict__ priv_i,
                                             int NP, int e4, int E) {
  int* my = priv_i + (size_t)xcc_id() * NP;
  int i = blockIdx.x * blockDim.x + threadIdx.x;
  if (i < e4) {
    int4 d = reinterpret_cast<const int4*>(dst)[i];
    atomicAdd(&my[d.x], 1);
    atomicAdd(&my[d.y], 1);
    atomicAdd(&my[d.z], 1);
    atomicAdd(&my[d.w], 1);
  }
  if (i == 0) {  // tail (E not multiple of 4) — no-op for E=6.4M
    for (int t = e4 * 4; t < E; ++t) atomicAdd(&my[dst[t]], 1);
  }
}

// ---- K2: reduce deg copies -> dinv; dropout1 -> y; re-zero priv ------------
__global__ __launch_bounds__(256) void k_node1(
    const float* __restrict__ x, int* __restrict__ priv_i,
    float* __restrict__ dinv, float* __restrict__ y,
    int NP, int n, unsigned k1a, unsigned k1b) {
  int i = blockIdx.x * blockDim.x + threadIdx.x;
  if (i >= n) return;
  int d = 0;
#pragma unroll
  for (int c = 0; c < COPIES; ++c) {
    d += priv_i[(size_t)c * NP + i];
    priv_i[(size_t)c * NP + i] = 0;  // floats 0.0f == int 0: ready for scat1
  }
  float di = (d > 0) ? (1.0f / sqrtf((float)d)) : 0.0f;
  dinv[i] = di;
  unsigned o0, o1;
  threefry2x32(k1a, k1b, 0u, (unsigned)i, o0, o1);
  float u = u01_from_bits(o0 ^ o1);   // partitionable 32-bit bits = out0 ^ out1
  float xd = (u < KEEP_P) ? (x[i] / KEEP_P) : 0.0f;
  y[i] = xd * di;
}

// ---- K3: scatter layer 1: priv[xcd][dst] += y[src] -------------------------
__global__ __launch_bounds__(256) void k_scat1(
    const int* __restrict__ src, const int* __restrict__ dst,
    const float* __restrict__ y, float* __restrict__ priv_f,
    int NP, int e4, int E) {
  float* my = priv_f + (size_t)xcc_id() * NP;
  int i = blockIdx.x * blockDim.x + threadIdx.x;
  if (i < e4) {
    int4 sv = reinterpret_cast<const int4*>(src)[i];
    int4 dv = reinterpret_cast<const int4*>(dst)[i];
    atomicAdd(&my[dv.x], y[sv.x]);
    atomicAdd(&my[dv.y], y[sv.y]);
    atomicAdd(&my[dv.z], y[sv.z]);
    atomicAdd(&my[dv.w], y[sv.w]);
  }
  if (i == 0) {
    for (int t = e4 * 4; t < E; ++t) atomicAdd(&my[dst[t]], y[src[t]]);
  }
}

// ---- K4: reduce s copies; layer1 epilogue + relu + dropout2 + W2 dot -------
__global__ __launch_bounds__(256) void k_node2(
    float* __restrict__ priv_f, const float* __restrict__ dinv,
    const float* __restrict__ W1, const float* __restrict__ b1,
    const float* __restrict__ W2, float* __restrict__ z2,
    int NP, int n, unsigned k2a, unsigned k2b) {
  int i = blockIdx.x * blockDim.x + threadIdx.x;
  if (i >= n) return;
  float s = 0.0f;
#pragma unroll
  for (int c = 0; c < COPIES; ++c) {
    s += priv_f[(size_t)c * NP + i];
    priv_f[(size_t)c * NP + i] = 0.0f;  // ready for scat2
  }
  float t = s * dinv[i];
  float z = 0.0f;
  unsigned base = (unsigned)i * 16u;
#pragma unroll
  for (int c = 0; c < 16; ++c) {
    float h = W1[c] * t + b1[c];
    h = fmaxf(h, 0.0f);
    unsigned o0, o1;
    threefry2x32(k2a, k2b, 0u, base + (unsigned)c, o0, o1);
    float u = u01_from_bits(o0 ^ o1); // partitionable 32-bit bits = out0 ^ out1
    float hd = (u < KEEP_P) ? (h / KEEP_P) : 0.0f;
    z += hd * W2[c];
  }
  z2[i] = z * dinv[i];   // dinv[dst] factor is applied in k_final instead
}

// ---- K5: scatter layer 2: priv[xcd][dst] += z2[src] ------------------------
__global__ __launch_bounds__(256) void k_scat2(
    const int* __restrict__ src, const int* __restrict__ dst,
    const float* __restrict__ z2, float* __restrict__ priv_f,
    int NP, int e4, int E) {
  float* my = priv_f + (size_t)xcc_id() * NP;
  int i = blockIdx.x * blockDim.x + threadIdx.x;
  if (i < e4) {
    int4 sv = reinterpret_cast<const int4*>(src)[i];
    int4 dv = reinterpret_cast<const int4*>(dst)[i];
    atomicAdd(&my[dv.x], z2[sv.x]);
    atomicAdd(&my[dv.y], z2[sv.y]);
    atomicAdd(&my[dv.z], z2[sv.z]);
    atomicAdd(&my[dv.w], z2[sv.w]);
  }
  if (i == 0) {
    for (int t = e4 * 4; t < E; ++t) atomicAdd(&my[dst[t]], z2[src[t]]);
  }
}

// ---- K6: final combine: out = b2 + dinv * sum(copies) ----------------------
__global__ __launch_bounds__(256) void k_final(
    const float* __restrict__ priv_f, const float* __restrict__ dinv,
    const float* __restrict__ b2, float* __restrict__ out, int NP, int n) {
  int i = blockIdx.x * blockDim.x + threadIdx.x;
  if (i >= n) return;
  float s = 0.0f;
#pragma unroll
  for (int c = 0; c < COPIES; ++c) s += priv_f[(size_t)c * NP + i];
  out[i] = b2[0] + dinv[i] * s;
}

extern "C" void kernel_launch(void* const* d_in, const int* in_sizes, int n_in,
                              void* d_out, int out_size, void* d_ws, size_t ws_size,
                              hipStream_t stream) {
  const float* x  = (const float*)d_in[0];
  const int* edge = (const int*)d_in[1];   // [2, E] int32 (harness canonicalizes int64)
  const float* W1 = (const float*)d_in[2]; // [1,16]
  const float* b1 = (const float*)d_in[3]; // [16]
  const float* W2 = (const float*)d_in[4]; // [16,1]
  const float* b2 = (const float*)d_in[5]; // [1]
  float* out = (float*)d_out;              // [N,1] f32

  const int N = in_sizes[0];
  const int E = in_sizes[1] / 2;
  const int* src = edge;
  const int* dst = edge + E;

  // Workspace: priv[8*NP] (reused: deg -> s -> out accumulators), dinv, y, z2
  const int NP = (N + 255) & ~255;
  int*   priv_i = (int*)d_ws;
  float* priv_f = (float*)d_ws;
  float* dinv = (float*)d_ws + (size_t)COPIES * NP;
  float* y    = dinv + NP;
  float* z2   = y + NP;

  // Derive dropout keys on host: foldlike split(key(42)), both output words.
  unsigned k1a, k1b, k2a, k2b;
  threefry2x32(0u, 42u, 0u, 0u, k1a, k1b);
  threefry2x32(0u, 42u, 0u, 1u, k2a, k2b);

  // Zero the private region once (ws is poisoned 0xAA before every call);
  // node kernels re-zero it between phases.
  hipMemsetAsync(d_ws, 0, (size_t)COPIES * NP * sizeof(int), stream);

  const int B = 256;
  const int e4 = E >> 2;
  const int gE = (e4 + B - 1) / B;
  const int gN = (N + B - 1) / B;

  k_deg  <<<gE, B, 0, stream>>>(dst, priv_i, NP, e4, E);
  k_node1<<<gN, B, 0, stream>>>(x, priv_i, dinv, y, NP, N, k1a, k1b);
  k_scat1<<<gE, B, 0, stream>>>(src, dst, y, priv_f, NP, e4, E);
  k_node2<<<gN, B, 0, stream>>>(priv_f, dinv, W1, b1, W2, z2, NP, N, k2a, k2b);
  k_scat2<<<gE, B, 0, stream>>>(src, dst, z2, priv_f, NP, e4, E);
  k_final<<<gN, B, 0, stream>>>(priv_f, dinv, b2, out, NP, N);
}

// Round 4
// 963.874 us; speedup vs baseline: 1.0433x; 1.0002x over previous
//
#include <hip/hip_runtime.h>
#include <hip/hip_bf16.h>
#include <stdint.h>

// GCN forward, collapsed to scalar form (W1:[1,16], W2:[16,1] are rank-1).
// R4 change: per-XCD privatized accumulators (R3) + WORKGROUP-scope atomics.
// R2/R3 counters showed WRITE_SIZE == E*32B regardless of privatization:
// default (agent-scope) atomicAdd is routed past the non-coherent per-XCD L2
// to memory-side atomic units by its scope bits. Since each private copy is
// only touched by one XCD, workgroup-scope relaxed atomics (no sc1 bit) are
// sufficient and should execute in the local XCD L2. Kernel-end agent release
// writes back L2, so the reduce kernels see the sums.

#define KEEP_P 0.4f
#define COPIES 8

__device__ inline unsigned xcc_id() {
  unsigned x;
  asm volatile("s_getreg_b32 %0, hwreg(HW_REG_XCC_ID)" : "=s"(x));
  return x & 7u;
}

__device__ inline void atomic_add_l2(float* p, float v) {
  __hip_atomic_fetch_add(p, v, __ATOMIC_RELAXED, __HIP_MEMORY_SCOPE_WORKGROUP);
}
__device__ inline void atomic_add_l2(int* p, int v) {
  __hip_atomic_fetch_add(p, v, __ATOMIC_RELAXED, __HIP_MEMORY_SCOPE_WORKGROUP);
}

__host__ __device__ inline unsigned rotl32(unsigned v, int s) {
  return (v << s) | (v >> (32 - s));
}

__host__ __device__ inline void threefry2x32(unsigned key0, unsigned key1,
                                             unsigned x0, unsigned x1,
                                             unsigned& o0, unsigned& o1) {
  unsigned ks0 = key0, ks1 = key1, ks2 = key0 ^ key1 ^ 0x1BD11BDAu;
  unsigned v0 = x0 + ks0, v1 = x1 + ks1;
#define TF_R(r) { v0 += v1; v1 = rotl32(v1, r); v1 ^= v0; }
  TF_R(13) TF_R(15) TF_R(26) TF_R(6)
  v0 += ks1; v1 += ks2 + 1u;
  TF_R(17) TF_R(29) TF_R(16) TF_R(24)
  v0 += ks2; v1 += ks0 + 2u;
  TF_R(13) TF_R(15) TF_R(26) TF_R(6)
  v0 += ks0; v1 += ks1 + 3u;
  TF_R(17) TF_R(29) TF_R(16) TF_R(24)
  v0 += ks1; v1 += ks2 + 4u;
  TF_R(13) TF_R(15) TF_R(26) TF_R(6)
  v0 += ks2; v1 += ks0 + 5u;
#undef TF_R
  o0 = v0; o1 = v1;
}

__device__ inline float u01_from_bits(unsigned bits) {
  return __uint_as_float((bits >> 9) | 0x3f800000u) - 1.0f;
}

// ---- K1: in-degree into per-XCD private copies -----------------------------
__global__ __launch_bounds__(256) void k_deg(const int* __restrict__ dst,
                                             int* __restrict__ priv_i,
                                             int NP, int e4, int E) {
  int* my = priv_i + (size_t)xcc_id() * NP;
  int i = blockIdx.x * blockDim.x + threadIdx.x;
  if (i < e4) {
    int4 d = reinterpret_cast<const int4*>(dst)[i];
    atomic_add_l2(&my[d.x], 1);
    atomic_add_l2(&my[d.y], 1);
    atomic_add_l2(&my[d.z], 1);
    atomic_add_l2(&my[d.w], 1);
  }
  if (i == 0) {  // tail (E not multiple of 4) — no-op for E=6.4M
    for (int t = e4 * 4; t < E; ++t) atomic_add_l2(&my[dst[t]], 1);
  }
}

// ---- K2: reduce deg copies -> dinv; dropout1 -> y; re-zero priv ------------
__global__ __launch_bounds__(256) void k_node1(
    const float* __restrict__ x, int* __restrict__ priv_i,
    float* __restrict__ dinv, float* __restrict__ y,
    int NP, int n, unsigned k1a, unsigned k1b) {
  int i = blockIdx.x * blockDim.x + threadIdx.x;
  if (i >= n) return;
  int d = 0;
#pragma unroll
  for (int c = 0; c < COPIES; ++c) {
    d += priv_i[(size_t)c * NP + i];
    priv_i[(size_t)c * NP + i] = 0;  // float 0.0f == int 0: ready for scat1
  }
  float di = (d > 0) ? (1.0f / sqrtf((float)d)) : 0.0f;
  dinv[i] = di;
  unsigned o0, o1;
  threefry2x32(k1a, k1b, 0u, (unsigned)i, o0, o1);
  float u = u01_from_bits(o0 ^ o1);   // partitionable 32-bit bits = out0 ^ out1
  float xd = (u < KEEP_P) ? (x[i] / KEEP_P) : 0.0f;
  y[i] = xd * di;
}

// ---- K3: scatter layer 1: priv[xcd][dst] += y[src] -------------------------
__global__ __launch_bounds__(256) void k_scat1(
    const int* __restrict__ src, const int* __restrict__ dst,
    const float* __restrict__ y, float* __restrict__ priv_f,
    int NP, int e4, int E) {
  float* my = priv_f + (size_t)xcc_id() * NP;
  int i = blockIdx.x * blockDim.x + threadIdx.x;
  if (i < e4) {
    int4 sv = reinterpret_cast<const int4*>(src)[i];
    int4 dv = reinterpret_cast<const int4*>(dst)[i];
    atomic_add_l2(&my[dv.x], y[sv.x]);
    atomic_add_l2(&my[dv.y], y[sv.y]);
    atomic_add_l2(&my[dv.z], y[sv.z]);
    atomic_add_l2(&my[dv.w], y[sv.w]);
  }
  if (i == 0) {
    for (int t = e4 * 4; t < E; ++t) atomic_add_l2(&my[dst[t]], y[src[t]]);
  }
}

// ---- K4: reduce s copies; layer1 epilogue + relu + dropout2 + W2 dot -------
__global__ __launch_bounds__(256) void k_node2(
    float* __restrict__ priv_f, const float* __restrict__ dinv,
    const float* __restrict__ W1, const float* __restrict__ b1,
    const float* __restrict__ W2, float* __restrict__ z2,
    int NP, int n, unsigned k2a, unsigned k2b) {
  int i = blockIdx.x * blockDim.x + threadIdx.x;
  if (i >= n) return;
  float s = 0.0f;
#pragma unroll
  for (int c = 0; c < COPIES; ++c) {
    s += priv_f[(size_t)c * NP + i];
    priv_f[(size_t)c * NP + i] = 0.0f;  // ready for scat2
  }
  float t = s * dinv[i];
  float z = 0.0f;
  unsigned base = (unsigned)i * 16u;
#pragma unroll
  for (int c = 0; c < 16; ++c) {
    float h = W1[c] * t + b1[c];
    h = fmaxf(h, 0.0f);
    unsigned o0, o1;
    threefry2x32(k2a, k2b, 0u, base + (unsigned)c, o0, o1);
    float u = u01_from_bits(o0 ^ o1); // partitionable 32-bit bits = out0 ^ out1
    float hd = (u < KEEP_P) ? (h / KEEP_P) : 0.0f;
    z += hd * W2[c];
  }
  z2[i] = z * dinv[i];   // dinv[dst] factor is applied in k_final instead
}

// ---- K5: scatter layer 2: priv[xcd][dst] += z2[src] ------------------------
__global__ __launch_bounds__(256) void k_scat2(
    const int* __restrict__ src, const int* __restrict__ dst,
    const float* __restrict__ z2, float* __restrict__ priv_f,
    int NP, int e4, int E) {
  float* my = priv_f + (size_t)xcc_id() * NP;
  int i = blockIdx.x * blockDim.x + threadIdx.x;
  if (i < e4) {
    int4 sv = reinterpret_cast<const int4*>(src)[i];
    int4 dv = reinterpret_cast<const int4*>(dst)[i];
    atomic_add_l2(&my[dv.x], z2[sv.x]);
    atomic_add_l2(&my[dv.y], z2[sv.y]);
    atomic_add_l2(&my[dv.z], z2[sv.z]);
    atomic_add_l2(&my[dv.w], z2[sv.w]);
  }
  if (i == 0) {
    for (int t = e4 * 4; t < E; ++t) atomic_add_l2(&my[dst[t]], z2[src[t]]);
  }
}

// ---- K6: final combine: out = b2 + dinv * sum(copies) ----------------------
__global__ __launch_bounds__(256) void k_final(
    const float* __restrict__ priv_f, const float* __restrict__ dinv,
    const float* __restrict__ b2, float* __restrict__ out, int NP, int n) {
  int i = blockIdx.x * blockDim.x + threadIdx.x;
  if (i >= n) return;
  float s = 0.0f;
#pragma unroll
  for (int c = 0; c < COPIES; ++c) s += priv_f[(size_t)c * NP + i];
  out[i] = b2[0] + dinv[i] * s;
}

extern "C" void kernel_launch(void* const* d_in, const int* in_sizes, int n_in,
                              void* d_out, int out_size, void* d_ws, size_t ws_size,
                              hipStream_t stream) {
  const float* x  = (const float*)d_in[0];
  const int* edge = (const int*)d_in[1];   // [2, E] int32 (harness canonicalizes int64)
  const float* W1 = (const float*)d_in[2]; // [1,16]
  const float* b1 = (const float*)d_in[3]; // [16]
  const float* W2 = (const float*)d_in[4]; // [16,1]
  const float* b2 = (const float*)d_in[5]; // [1]
  float* out = (float*)d_out;              // [N,1] f32

  const int N = in_sizes[0];
  const int E = in_sizes[1] / 2;
  const int* src = edge;
  const int* dst = edge + E;

  // Workspace: priv[8*NP] (reused: deg -> s -> out accumulators), dinv, y, z2
  const int NP = (N + 255) & ~255;
  int*   priv_i = (int*)d_ws;
  float* priv_f = (float*)d_ws;
  float* dinv = (float*)d_ws + (size_t)COPIES * NP;
  float* y    = dinv + NP;
  float* z2   = y + NP;

  // Derive dropout keys on host: foldlike split(key(42)), both output words.
  unsigned k1a, k1b, k2a, k2b;
  threefry2x32(0u, 42u, 0u, 0u, k1a, k1b);
  threefry2x32(0u, 42u, 0u, 1u, k2a, k2b);

  // Zero the private region once (ws is poisoned 0xAA before every call);
  // node kernels re-zero it between phases.
  hipMemsetAsync(d_ws, 0, (size_t)COPIES * NP * sizeof(int), stream);

  const int B = 256;
  const int e4 = E >> 2;
  const int gE = (e4 + B - 1) / B;
  const int gN = (N + B - 1) / B;

  k_deg  <<<gE, B, 0, stream>>>(dst, priv_i, NP, e4, E);
  k_node1<<<gN, B, 0, stream>>>(x, priv_i, dinv, y, NP, N, k1a, k1b);
  k_scat1<<<gE, B, 0, stream>>>(src, dst, y, priv_f, NP, e4, E);
  k_node2<<<gN, B, 0, stream>>>(priv_f, dinv, W1, b1, W2, z2, NP, N, k2a, k2b);
  k_scat2<<<gE, B, 0, stream>>>(src, dst, z2, priv_f, NP, e4, E);
  k_final<<<gN, B, 0, stream>>>(priv_f, dinv, b2, out, NP, N);
}

// Round 5
// 392.989 us; speedup vs baseline: 2.5589x; 2.4527x over previous
//
#include <hip/hip_runtime.h>
#include <hip/hip_bf16.h>
#include <stdint.h>

// GCN forward, collapsed to scalar form (W1:[1,16], W2:[16,1] are rank-1).
// R5: ZERO global atomics. R2-R4 proved gfx950 global atomicAdd always
// executes memory-side (WRITE_SIZE == E*32B for shared, per-XCD-private, and
// workgroup-scope variants alike) at ~20 G atomics/s. Replaced with multipass
// LDS-privatized scatter: grid (B edge-slices x P node-ranges); block (b,p)
// streams edge slice b, LDS-atomics edges with dst in range p into 64 KB of
// bins, then flushes bins with plain coalesced stores to part[b]. Node
// kernels reduce the B partials. Edge list (51 MB) is LLC-resident, so the
// P-fold re-read is L3 traffic, not HBM. Degree pass: same structure, two
// u16 counts packed per u32 bin (max deg ~110 << 65535), 32K nodes/pass.

#define KEEP_P 0.4f
#define RANGE_F 16000   // f32 bins per pass (64 KB LDS)
#define RANGE_D 32000   // nodes per deg pass (16000 u32 bins, 2 nodes each)

__host__ __device__ inline unsigned rotl32(unsigned v, int s) {
  return (v << s) | (v >> (32 - s));
}

__host__ __device__ inline void threefry2x32(unsigned key0, unsigned key1,
                                             unsigned x0, unsigned x1,
                                             unsigned& o0, unsigned& o1) {
  unsigned ks0 = key0, ks1 = key1, ks2 = key0 ^ key1 ^ 0x1BD11BDAu;
  unsigned v0 = x0 + ks0, v1 = x1 + ks1;
#define TF_R(r) { v0 += v1; v1 = rotl32(v1, r); v1 ^= v0; }
  TF_R(13) TF_R(15) TF_R(26) TF_R(6)
  v0 += ks1; v1 += ks2 + 1u;
  TF_R(17) TF_R(29) TF_R(16) TF_R(24)
  v0 += ks2; v1 += ks0 + 2u;
  TF_R(13) TF_R(15) TF_R(26) TF_R(6)
  v0 += ks0; v1 += ks1 + 3u;
  TF_R(17) TF_R(29) TF_R(16) TF_R(24)
  v0 += ks1; v1 += ks2 + 4u;
  TF_R(13) TF_R(15) TF_R(26) TF_R(6)
  v0 += ks2; v1 += ks0 + 5u;
#undef TF_R
  o0 = v0; o1 = v1;
}

__device__ inline float u01_from_bits(unsigned bits) {
  return __uint_as_float((bits >> 9) | 0x3f800000u) - 1.0f;
}

// ---- K1: degree histogram, LDS-binned, u16-packed --------------------------
// grid (B, P_deg); block (b,p): edges of slice b with dst in [p*RANGE_D, ...)
__global__ __launch_bounds__(256) void k_deg(
    const int* __restrict__ dst, unsigned short* __restrict__ part16,
    int NP, int e4, int E, int N) {
  __shared__ unsigned bins[RANGE_D / 2];  // 64000 B
  const int tid = threadIdx.x;
  const int lo = blockIdx.y * RANGE_D;
  const int hi = min(lo + RANGE_D, N);
  for (int i = tid; i < RANGE_D / 2; i += 256) bins[i] = 0u;
  __syncthreads();

  const int B = gridDim.x;
  const int chunk = (e4 + B - 1) / B;
  const int j0 = blockIdx.x * chunk;
  const int j1 = min(j0 + chunk, e4);
  const int4* dst4 = reinterpret_cast<const int4*>(dst);
#define DEG_ONE(d) { int r = (d) - lo; if ((unsigned)r < (unsigned)(hi - lo)) \
    atomicAdd(&bins[r >> 1], 1u << ((r & 1) * 16)); }
  for (int j = j0 + tid; j < j1; j += 256) {
    int4 d = dst4[j];
    DEG_ONE(d.x) DEG_ONE(d.y) DEG_ONE(d.z) DEG_ONE(d.w)
  }
  if (blockIdx.x == 0) {  // tail when E%4 != 0 (dead for E=6.4M)
    for (int t = e4 * 4 + tid; t < E; t += 256) DEG_ONE(dst[t])
  }
#undef DEG_ONE
  __syncthreads();
  unsigned short* my = part16 + (size_t)blockIdx.x * NP;
  for (int i = tid; i < hi - lo; i += 256)
    my[lo + i] = (unsigned short)((bins[i >> 1] >> ((i & 1) * 16)) & 0xFFFFu);
}

// ---- K2: reduce deg partials -> dinv; dropout1 -> y ------------------------
__global__ __launch_bounds__(256) void k_node1(
    const float* __restrict__ x, const unsigned short* __restrict__ part16,
    float* __restrict__ dinv, float* __restrict__ y,
    int NP, int n, int B, unsigned k1a, unsigned k1b) {
  int i = blockIdx.x * blockDim.x + threadIdx.x;
  if (i >= n) return;
  unsigned d = 0;
  for (int b = 0; b < B; ++b) d += part16[(size_t)b * NP + i];
  float di = (d > 0) ? (1.0f / sqrtf((float)d)) : 0.0f;
  dinv[i] = di;
  unsigned o0, o1;
  threefry2x32(k1a, k1b, 0u, (unsigned)i, o0, o1);
  float u = u01_from_bits(o0 ^ o1);   // partitionable 32-bit bits = out0 ^ out1
  float xd = (u < KEEP_P) ? (x[i] / KEEP_P) : 0.0f;
  y[i] = xd * di;
}

// ---- K3/K5: generic LDS-binned scatter: part[b][n] = sum of val[src] -------
// grid (B, P_f); block (b,p): edges of slice b with dst in [p*RANGE_F, ...)
__global__ __launch_bounds__(256) void k_scat(
    const int* __restrict__ src, const int* __restrict__ dst,
    const float* __restrict__ val, float* __restrict__ part,
    int NP, int e4, int E, int N) {
  __shared__ float bins[RANGE_F];  // 64000 B
  const int tid = threadIdx.x;
  const int lo = blockIdx.y * RANGE_F;
  const int hi = min(lo + RANGE_F, N);
  for (int i = tid; i < RANGE_F; i += 256) bins[i] = 0.0f;
  __syncthreads();

  const int B = gridDim.x;
  const int chunk = (e4 + B - 1) / B;
  const int j0 = blockIdx.x * chunk;
  const int j1 = min(j0 + chunk, e4);
  const int4* dst4 = reinterpret_cast<const int4*>(dst);
  const int4* src4 = reinterpret_cast<const int4*>(src);
#define SC_ONE(d, s) { int r = (d) - lo; if ((unsigned)r < (unsigned)(hi - lo)) \
    atomicAdd(&bins[r], val[(s)]); }
  for (int j = j0 + tid; j < j1; j += 256) {
    int4 d = dst4[j];
    int4 s = src4[j];
    SC_ONE(d.x, s.x) SC_ONE(d.y, s.y) SC_ONE(d.z, s.z) SC_ONE(d.w, s.w)
  }
  if (blockIdx.x == 0) {  // tail when E%4 != 0 (dead for E=6.4M)
    for (int t = e4 * 4 + tid; t < E; t += 256) SC_ONE(dst[t], src[t])
  }
#undef SC_ONE
  __syncthreads();
  float* my = part + (size_t)blockIdx.x * NP;
  for (int i = tid; i < hi - lo; i += 256) my[lo + i] = bins[i];
}

// ---- K4: reduce s partials; layer1 epilogue + relu + dropout2 + W2 dot -----
__global__ __launch_bounds__(256) void k_node2(
    const float* __restrict__ part, const float* __restrict__ dinv,
    const float* __restrict__ W1, const float* __restrict__ b1,
    const float* __restrict__ W2, float* __restrict__ z2,
    int NP, int n, int B, unsigned k2a, unsigned k2b) {
  int i = blockIdx.x * blockDim.x + threadIdx.x;
  if (i >= n) return;
  float s = 0.0f;
  for (int b = 0; b < B; ++b) s += part[(size_t)b * NP + i];
  float t = s * dinv[i];
  float z = 0.0f;
  unsigned base = (unsigned)i * 16u;
#pragma unroll
  for (int c = 0; c < 16; ++c) {
    float h = W1[c] * t + b1[c];
    h = fmaxf(h, 0.0f);
    unsigned o0, o1;
    threefry2x32(k2a, k2b, 0u, base + (unsigned)c, o0, o1);
    float u = u01_from_bits(o0 ^ o1); // partitionable 32-bit bits = out0 ^ out1
    float hd = (u < KEEP_P) ? (h / KEEP_P) : 0.0f;
    z += hd * W2[c];
  }
  z2[i] = z * dinv[i];   // dinv[dst] factor applied in k_final
}

// ---- K6: final combine: out = b2 + dinv * sum(partials) --------------------
__global__ __launch_bounds__(256) void k_final(
    const float* __restrict__ part, const float* __restrict__ dinv,
    const float* __restrict__ b2, float* __restrict__ out,
    int NP, int n, int B) {
  int i = blockIdx.x * blockDim.x + threadIdx.x;
  if (i >= n) return;
  float s = 0.0f;
  for (int b = 0; b < B; ++b) s += part[(size_t)b * NP + i];
  out[i] = b2[0] + dinv[i] * s;
}

extern "C" void kernel_launch(void* const* d_in, const int* in_sizes, int n_in,
                              void* d_out, int out_size, void* d_ws, size_t ws_size,
                              hipStream_t stream) {
  const float* x  = (const float*)d_in[0];
  const int* edge = (const int*)d_in[1];   // [2, E] int32 (harness canonicalizes int64)
  const float* W1 = (const float*)d_in[2]; // [1,16]
  const float* b1 = (const float*)d_in[3]; // [16]
  const float* W2 = (const float*)d_in[4]; // [16,1]
  const float* b2 = (const float*)d_in[5]; // [1]
  float* out = (float*)d_out;              // [N,1] f32

  const int N = in_sizes[0];
  const int E = in_sizes[1] / 2;
  const int* src = edge;
  const int* dst = edge + E;

  const int NP = (N + 255) & ~255;

  // Adaptive number of edge slices B: part_f (B*NP f32) + part16 (B*NP u16)
  // + dinv,y,z2 (3*NP f32) must fit ws_size. Target B=64.
  size_t fixed = (size_t)3 * NP * 4;
  int B = 64;
  if (ws_size > fixed) {
    size_t bmax = (ws_size - fixed) / ((size_t)NP * 6);
    if ((size_t)B > bmax) B = (int)bmax;
  } else {
    B = 1;
  }
  if (B < 1) B = 1;

  float* part_f = (float*)d_ws;                               // [B][NP] f32
  unsigned short* part16 =
      (unsigned short*)((char*)d_ws + (size_t)B * NP * 4);    // [B][NP] u16
  float* dinv = (float*)((char*)d_ws + (size_t)B * NP * 6);
  float* y    = dinv + NP;
  float* z2   = y + NP;

  // Dropout keys: foldlike split(key(42)) under partitionable threefry.
  unsigned k1a, k1b, k2a, k2b;
  threefry2x32(0u, 42u, 0u, 0u, k1a, k1b);
  threefry2x32(0u, 42u, 0u, 1u, k2a, k2b);

  const int e4 = E >> 2;
  const int Pd = (N + RANGE_D - 1) / RANGE_D;
  const int Pf = (N + RANGE_F - 1) / RANGE_F;
  const int gN = (N + 255) / 256;

  k_deg  <<<dim3(B, Pd), 256, 0, stream>>>(dst, part16, NP, e4, E, N);
  k_node1<<<gN, 256, 0, stream>>>(x, part16, dinv, y, NP, N, B, k1a, k1b);
  k_scat <<<dim3(B, Pf), 256, 0, stream>>>(src, dst, y, part_f, NP, e4, E, N);
  k_node2<<<gN, 256, 0, stream>>>(part_f, dinv, W1, b1, W2, z2, NP, N, B, k2a, k2b);
  k_scat <<<dim3(B, Pf), 256, 0, stream>>>(src, dst, z2, part_f, NP, e4, E, N);
  k_final<<<gN, 256, 0, stream>>>(part_f, dinv, b2, out, NP, N, B);
}

// Round 6
// 306.587 us; speedup vs baseline: 3.2801x; 1.2818x over previous
//
#include <hip/hip_runtime.h>
#include <hip/hip_bf16.h>
#include <stdint.h>

// GCN forward, collapsed to scalar form (W1:[1,16], W2:[16,1] are rank-1).
// R6: one-shot radix partition of the edge list by dst range, then
// single-pass LDS-binned scatters. R5 was latency-bound (Occ 17%, VALU 7%,
// HBM 5.6%): each block re-read its edge slice Pf=7 times and 64 KB LDS
// capped occupancy at 2 blocks/CU. Now:
//   k_count:  per-block per-bucket edge histogram (LDS, per-wave counters)
//   k_scan:   exclusive scan of [NB][Bp] counts -> per-block cursors + bstart
//   k_part:   write each edge once, packed u32 = (dst&16383)|(src<<14),
//             into its bucket segment (LDS cursors)
//   k_deg2:   degree from packed buckets, u16-packed 32 KB LDS bins
//   k_node1:  reduce deg partials -> dinv; dropout1 -> y
//   k_scat:   per bucket: bins[r] += val[s] (LDS atomics), 4-deep unroll,
//             flush to per-(block-in-bucket) partials
//   k_node2:  reduce partials; relu+dropout2+W2 dot -> z2
//   k_scat:   layer 2, val = z2
//   k_final:  out = b2 + dinv * sum(partials)
// No global atomics anywhere (R2-R4: gfx950 global atomics are memory-side,
// ~20 G/s, WRITE_SIZE = E*32B regardless of privatization/scope).
// Requires N <= 262144 (src fits 18 bits); N=100000 here.

#define KEEP_P 0.4f
#define RANGE 16384
#define SHIFT 14
#define MASK 16383
#define BP 256          // count/partition blocks

__host__ __device__ inline unsigned rotl32(unsigned v, int s) {
  return (v << s) | (v >> (32 - s));
}

__host__ __device__ inline void threefry2x32(unsigned key0, unsigned key1,
                                             unsigned x0, unsigned x1,
                                             unsigned& o0, unsigned& o1) {
  unsigned ks0 = key0, ks1 = key1, ks2 = key0 ^ key1 ^ 0x1BD11BDAu;
  unsigned v0 = x0 + ks0, v1 = x1 + ks1;
#define TF_R(r) { v0 += v1; v1 = rotl32(v1, r); v1 ^= v0; }
  TF_R(13) TF_R(15) TF_R(26) TF_R(6)
  v0 += ks1; v1 += ks2 + 1u;
  TF_R(17) TF_R(29) TF_R(16) TF_R(24)
  v0 += ks2; v1 += ks0 + 2u;
  TF_R(13) TF_R(15) TF_R(26) TF_R(6)
  v0 += ks0; v1 += ks1 + 3u;
  TF_R(17) TF_R(29) TF_R(16) TF_R(24)
  v0 += ks1; v1 += ks2 + 4u;
  TF_R(13) TF_R(15) TF_R(26) TF_R(6)
  v0 += ks2; v1 += ks0 + 5u;
#undef TF_R
  o0 = v0; o1 = v1;
}

__device__ inline float u01_from_bits(unsigned bits) {
  return __uint_as_float((bits >> 9) | 0x3f800000u) - 1.0f;
}

// ---- K1: per-block per-bucket histogram ------------------------------------
__global__ __launch_bounds__(256) void k_count(
    const int* __restrict__ dst, unsigned* __restrict__ counts,
    int NB, int e4, int E) {
  __shared__ unsigned cnt[4][32];  // per-wave counters, NB <= 32
  const int tid = threadIdx.x, w = tid >> 6;
  for (int i = tid; i < 4 * 32; i += 256) ((unsigned*)cnt)[i] = 0u;
  __syncthreads();
  const int chunk = (e4 + BP - 1) / BP;
  const int j0 = blockIdx.x * chunk;
  const int j1 = min(j0 + chunk, e4);
  const int4* dst4 = reinterpret_cast<const int4*>(dst);
  for (int j = j0 + tid; j < j1; j += 256) {
    int4 d = dst4[j];
    atomicAdd(&cnt[w][(unsigned)d.x >> SHIFT], 1u);
    atomicAdd(&cnt[w][(unsigned)d.y >> SHIFT], 1u);
    atomicAdd(&cnt[w][(unsigned)d.z >> SHIFT], 1u);
    atomicAdd(&cnt[w][(unsigned)d.w >> SHIFT], 1u);
  }
  if (blockIdx.x == 0) {  // tail when E%4 != 0
    for (int t = e4 * 4 + tid; t < E; t += 256)
      atomicAdd(&cnt[w][(unsigned)dst[t] >> SHIFT], 1u);
  }
  __syncthreads();
  // counts laid out bucket-major: counts[p*BP + b]
  for (int p = tid; p < NB; p += 256)
    counts[p * BP + blockIdx.x] = cnt[0][p] + cnt[1][p] + cnt[2][p] + cnt[3][p];
}

// ---- K2: exclusive scan of counts[NB*BP]; bstart[p] = scanned[p*BP] --------
__global__ __launch_bounds__(256) void k_scan(
    unsigned* __restrict__ counts, int* __restrict__ bstart,
    int T, int NB, int E) {
  __shared__ unsigned ssum[256];
  const int tid = threadIdx.x;
  const int per = (T + 255) / 256;  // <= 16
  unsigned local[16];
  unsigned sum = 0;
  for (int k = 0; k < per; ++k) {
    int idx = tid * per + k;
    unsigned v = (idx < T) ? counts[idx] : 0u;
    local[k] = sum;
    sum += v;
  }
  ssum[tid] = sum;
  __syncthreads();
  if (tid == 0) {
    unsigned acc = 0;
    for (int i = 0; i < 256; ++i) { unsigned v = ssum[i]; ssum[i] = acc; acc += v; }
  }
  __syncthreads();
  unsigned base = ssum[tid];
  for (int k = 0; k < per; ++k) {
    int idx = tid * per + k;
    if (idx < T) {
      unsigned ex = base + local[k];
      counts[idx] = ex;                       // in-place exclusive scan
      if ((idx & (BP - 1)) == 0) bstart[idx / BP] = (int)ex;
    }
  }
  if (tid == 0) bstart[NB] = E;
}

// ---- K3: partition edges into bucket segments, packed u32 ------------------
__global__ __launch_bounds__(256) void k_part(
    const int* __restrict__ src, const int* __restrict__ dst,
    const unsigned* __restrict__ base, unsigned* __restrict__ packed,
    int NB, int e4, int E) {
  __shared__ unsigned cur[32];
  const int tid = threadIdx.x;
  for (int p = tid; p < NB; p += 256) cur[p] = base[p * BP + blockIdx.x];
  __syncthreads();
  const int chunk = (e4 + BP - 1) / BP;
  const int j0 = blockIdx.x * chunk;
  const int j1 = min(j0 + chunk, e4);
  const int4* dst4 = reinterpret_cast<const int4*>(dst);
  const int4* src4 = reinterpret_cast<const int4*>(src);
#define PART_ONE(d, s) { unsigned p = (unsigned)(d) >> SHIFT; \
    unsigned pos = atomicAdd(&cur[p], 1u); \
    packed[pos] = ((unsigned)(d) & MASK) | ((unsigned)(s) << SHIFT); }
  for (int j = j0 + tid; j < j1; j += 256) {
    int4 d = dst4[j];
    int4 s = src4[j];
    PART_ONE(d.x, s.x) PART_ONE(d.y, s.y) PART_ONE(d.z, s.z) PART_ONE(d.w, s.w)
  }
  if (blockIdx.x == 0) {  // tail when E%4 != 0
    for (int t = e4 * 4 + tid; t < E; t += 256) PART_ONE(dst[t], src[t])
  }
#undef PART_ONE
}

// ---- K4: degree from packed buckets, u16-packed bins (32 KB) ---------------
__global__ __launch_bounds__(256) void k_deg2(
    const unsigned* __restrict__ packed, const int* __restrict__ bstart,
    unsigned short* __restrict__ part16, int NP, int Kd, int N) {
  __shared__ unsigned bins[RANGE / 2];  // 32 KB
  const int tid = threadIdx.x;
  const int p = blockIdx.y, kd = blockIdx.x;
  const int lo = p * RANGE;
  const int hi = min(lo + RANGE, N);
  for (int i = tid; i < RANGE / 2; i += 256) bins[i] = 0u;
  __syncthreads();
  const int s0 = bstart[p], s1 = bstart[p + 1];
  const int chunk = (s1 - s0 + Kd - 1) / Kd;
  const int j0 = s0 + kd * chunk;
  const int j1 = min(j0 + chunk, s1);
  int j = j0 + tid;
  for (; j + 768 < j1; j += 1024) {
    unsigned v0 = packed[j], v1 = packed[j + 256];
    unsigned v2 = packed[j + 512], v3 = packed[j + 768];
    unsigned r0 = v0 & MASK, r1 = v1 & MASK, r2 = v2 & MASK, r3 = v3 & MASK;
    atomicAdd(&bins[r0 >> 1], 1u << ((r0 & 1) * 16));
    atomicAdd(&bins[r1 >> 1], 1u << ((r1 & 1) * 16));
    atomicAdd(&bins[r2 >> 1], 1u << ((r2 & 1) * 16));
    atomicAdd(&bins[r3 >> 1], 1u << ((r3 & 1) * 16));
  }
  for (; j < j1; j += 256) {
    unsigned r = packed[j] & MASK;
    atomicAdd(&bins[r >> 1], 1u << ((r & 1) * 16));
  }
  __syncthreads();
  unsigned short* my = part16 + (size_t)kd * NP;
  for (int i = tid; i < hi - lo; i += 256)
    my[lo + i] = (unsigned short)((bins[i >> 1] >> ((i & 1) * 16)) & 0xFFFFu);
}

// ---- K5: reduce deg partials -> dinv; dropout1 -> y ------------------------
__global__ __launch_bounds__(256) void k_node1(
    const float* __restrict__ x, const unsigned short* __restrict__ part16,
    float* __restrict__ dinv, float* __restrict__ y,
    int NP, int n, int Kd, unsigned k1a, unsigned k1b) {
  int i = blockIdx.x * blockDim.x + threadIdx.x;
  if (i >= n) return;
  unsigned d = 0;
  for (int b = 0; b < Kd; ++b) d += part16[(size_t)b * NP + i];
  float di = (d > 0) ? (1.0f / sqrtf((float)d)) : 0.0f;
  dinv[i] = di;
  unsigned o0, o1;
  threefry2x32(k1a, k1b, 0u, (unsigned)i, o0, o1);
  float u = u01_from_bits(o0 ^ o1);   // partitionable 32-bit bits = out0 ^ out1
  float xd = (u < KEEP_P) ? (x[i] / KEEP_P) : 0.0f;
  y[i] = xd * di;
}

// ---- K6/K8: binned scatter from packed bucket: bins[r] += val[s] -----------
__global__ __launch_bounds__(256) void k_scat(
    const unsigned* __restrict__ packed, const int* __restrict__ bstart,
    const float* __restrict__ val, float* __restrict__ part,
    int NP, int Ks, int N) {
  __shared__ float bins[RANGE];  // 64 KB
  const int tid = threadIdx.x;
  const int p = blockIdx.y, ks = blockIdx.x;
  const int lo = p * RANGE;
  const int hi = min(lo + RANGE, N);
  for (int i = tid; i < RANGE; i += 256) bins[i] = 0.0f;
  __syncthreads();
  const int s0 = bstart[p], s1 = bstart[p + 1];
  const int chunk = (s1 - s0 + Ks - 1) / Ks;
  const int j0 = s0 + ks * chunk;
  const int j1 = min(j0 + chunk, s1);
  int j = j0 + tid;
  for (; j + 768 < j1; j += 1024) {
    unsigned v0 = packed[j], v1 = packed[j + 256];
    unsigned v2 = packed[j + 512], v3 = packed[j + 768];
    float a0 = val[v0 >> SHIFT], a1 = val[v1 >> SHIFT];
    float a2 = val[v2 >> SHIFT], a3 = val[v3 >> SHIFT];
    atomicAdd(&bins[v0 & MASK], a0);
    atomicAdd(&bins[v1 & MASK], a1);
    atomicAdd(&bins[v2 & MASK], a2);
    atomicAdd(&bins[v3 & MASK], a3);
  }
  for (; j < j1; j += 256) {
    unsigned v = packed[j];
    atomicAdd(&bins[v & MASK], val[v >> SHIFT]);
  }
  __syncthreads();
  float* my = part + (size_t)ks * NP;
  for (int i = tid; i < hi - lo; i += 256) my[lo + i] = bins[i];
}

// ---- K7: reduce s partials; layer1 epilogue + relu + dropout2 + W2 dot -----
__global__ __launch_bounds__(256) void k_node2(
    const float* __restrict__ part, const float* __restrict__ dinv,
    const float* __restrict__ W1, const float* __restrict__ b1,
    const float* __restrict__ W2, float* __restrict__ z2,
    int NP, int n, int Ks, unsigned k2a, unsigned k2b) {
  int i = blockIdx.x * blockDim.x + threadIdx.x;
  if (i >= n) return;
  float s = 0.0f;
  for (int b = 0; b < Ks; ++b) s += part[(size_t)b * NP + i];
  float t = s * dinv[i];
  float z = 0.0f;
  unsigned base = (unsigned)i * 16u;
#pragma unroll
  for (int c = 0; c < 16; ++c) {
    float h = W1[c] * t + b1[c];
    h = fmaxf(h, 0.0f);
    unsigned o0, o1;
    threefry2x32(k2a, k2b, 0u, base + (unsigned)c, o0, o1);
    float u = u01_from_bits(o0 ^ o1);
    float hd = (u < KEEP_P) ? (h / KEEP_P) : 0.0f;
    z += hd * W2[c];
  }
  z2[i] = z * dinv[i];   // dinv[dst] factor applied in k_final
}

// ---- K9: final combine: out = b2 + dinv * sum(partials) --------------------
__global__ __launch_bounds__(256) void k_final(
    const float* __restrict__ part, const float* __restrict__ dinv,
    const float* __restrict__ b2, float* __restrict__ out,
    int NP, int n, int Ks) {
  int i = blockIdx.x * blockDim.x + threadIdx.x;
  if (i >= n) return;
  float s = 0.0f;
  for (int b = 0; b < Ks; ++b) s += part[(size_t)b * NP + i];
  out[i] = b2[0] + dinv[i] * s;
}

extern "C" void kernel_launch(void* const* d_in, const int* in_sizes, int n_in,
                              void* d_out, int out_size, void* d_ws, size_t ws_size,
                              hipStream_t stream) {
  const float* x  = (const float*)d_in[0];
  const int* edge = (const int*)d_in[1];   // [2, E] int32
  const float* W1 = (const float*)d_in[2]; // [1,16]
  const float* b1 = (const float*)d_in[3]; // [16]
  const float* W2 = (const float*)d_in[4]; // [16,1]
  const float* b2 = (const float*)d_in[5]; // [1]
  float* out = (float*)d_out;              // [N,1] f32

  const int N = in_sizes[0];
  const int E = in_sizes[1] / 2;
  const int* src = edge;
  const int* dst = edge + E;

  const int NP = (N + 255) & ~255;
  const int NB = (N + RANGE - 1) / RANGE;   // 7 for N=100K (NB <= 32 assumed)

  // ws layout: [packed E u32][counts NB*BP u32][bstart NB+1 int]
  //            [partials: Ks*NP f32, aliased by Kd*NP u16][dinv][y][z2]
  char* w = (char*)d_ws;
  unsigned* packed = (unsigned*)w;            w += (size_t)E * 4;
  unsigned* counts = (unsigned*)w;            w += (size_t)NB * BP * 4;
  int* bstart = (int*)w;                      w += (size_t)(NB + 1) * 4;
  w = (char*)(((uintptr_t)w + 255) & ~(uintptr_t)255);
  size_t used = (size_t)(w - (char*)d_ws);
  size_t smallB = (size_t)3 * NP * 4;
  int Ks = 8;
  if (ws_size > used + smallB) {
    size_t bmax = (ws_size - used - smallB) / ((size_t)NP * 4);
    Ks = (int)(bmax < 64 ? bmax : 64);
  }
  if (Ks < 1) Ks = 1;
  int Kd = Ks * 2 <= 128 ? Ks * 2 : 128;      // u16 partials: half the bytes
  float* part_f = (float*)w;
  unsigned short* part16 = (unsigned short*)w;  // aliased (deg phase ends first)
  float* dinv = (float*)(w + (size_t)Ks * NP * 4);
  float* y    = dinv + NP;
  float* z2   = y + NP;

  // Dropout keys: foldlike split(key(42)) under partitionable threefry.
  unsigned k1a, k1b, k2a, k2b;
  threefry2x32(0u, 42u, 0u, 0u, k1a, k1b);
  threefry2x32(0u, 42u, 0u, 1u, k2a, k2b);

  const int e4 = E >> 2;
  const int gN = (N + 255) / 256;

  k_count<<<BP, 256, 0, stream>>>(dst, counts, NB, e4, E);
  k_scan <<<1, 256, 0, stream>>>(counts, bstart, NB * BP, NB, E);
  k_part <<<BP, 256, 0, stream>>>(src, dst, counts, packed, NB, e4, E);
  k_deg2 <<<dim3(Kd, NB), 256, 0, stream>>>(packed, bstart, part16, NP, Kd, N);
  k_node1<<<gN, 256, 0, stream>>>(x, part16, dinv, y, NP, N, Kd, k1a, k1b);
  k_scat <<<dim3(Ks, NB), 256, 0, stream>>>(packed, bstart, y, part_f, NP, Ks, N);
  k_node2<<<gN, 256, 0, stream>>>(part_f, dinv, W1, b1, W2, z2, NP, N, Ks, k2a, k2b);
  k_scat <<<dim3(Ks, NB), 256, 0, stream>>>(packed, bstart, z2, part_f, NP, Ks, N);
  k_final<<<gN, 256, 0, stream>>>(part_f, dinv, b2, out, NP, N, Ks);
}

// Round 7
// 304.937 us; speedup vs baseline: 3.2979x; 1.0054x over previous
//
#include <hip/hip_runtime.h>
#include <hip/hip_bf16.h>
#include <stdint.h>

// GCN forward, collapsed to scalar form (W1:[1,16], W2:[16,1] are rank-1).
// R7 (on R6's one-shot radix partition + single-pass LDS-binned scatters):
//   - RANGE 8192 (32 KB f32 bins): 13 buckets, grid Ks*13=832, ~3.3 blk/CU
//     (R6: 64 KB bins -> 2 blk/CU, Occ 12.6%, latency-bound at 50 us/scat)
//   - k_part: per-(block,wave) cursors. R6 had 1024 threads LDS-atomicAdd
//     onto 7 shared words -> cross-wave same-address serialization.
//   - k_deg2: Kd=64, 16 KB u16-packed bins, u32-pair flush (R6 Kd=128 spent
//     more on zero+flush than on edges).
//   - 8-deep gather unroll in k_scat/k_deg2.
// No global atomics anywhere (R2-R4: gfx950 global atomic RMW is always
// memory-side, ~20 G/s, WRITE_SIZE=E*32B regardless of privatization/scope).
// Packing: u32 = (dst&8191) | (src<<13); requires N <= 524288 (N=100K).

#define KEEP_P 0.4f
#define RANGE 8192
#define SHIFT 13
#define MASK 8191
#define BP 256          // count/partition blocks
#define NBMAX 16

__host__ __device__ inline unsigned rotl32(unsigned v, int s) {
  return (v << s) | (v >> (32 - s));
}

__host__ __device__ inline void threefry2x32(unsigned key0, unsigned key1,
                                             unsigned x0, unsigned x1,
                                             unsigned& o0, unsigned& o1) {
  unsigned ks0 = key0, ks1 = key1, ks2 = key0 ^ key1 ^ 0x1BD11BDAu;
  unsigned v0 = x0 + ks0, v1 = x1 + ks1;
#define TF_R(r) { v0 += v1; v1 = rotl32(v1, r); v1 ^= v0; }
  TF_R(13) TF_R(15) TF_R(26) TF_R(6)
  v0 += ks1; v1 += ks2 + 1u;
  TF_R(17) TF_R(29) TF_R(16) TF_R(24)
  v0 += ks2; v1 += ks0 + 2u;
  TF_R(13) TF_R(15) TF_R(26) TF_R(6)
  v0 += ks0; v1 += ks1 + 3u;
  TF_R(17) TF_R(29) TF_R(16) TF_R(24)
  v0 += ks1; v1 += ks2 + 4u;
  TF_R(13) TF_R(15) TF_R(26) TF_R(6)
  v0 += ks2; v1 += ks0 + 5u;
#undef TF_R
  o0 = v0; o1 = v1;
}

__device__ inline float u01_from_bits(unsigned bits) {
  return __uint_as_float((bits >> 9) | 0x3f800000u) - 1.0f;
}

// ---- K1: per-block per-wave per-bucket histogram ---------------------------
__global__ __launch_bounds__(256) void k_count(
    const int* __restrict__ dst, unsigned* __restrict__ counts,
    int NB, int e4, int E) {
  __shared__ unsigned cnt[4][NBMAX];
  const int tid = threadIdx.x, w = tid >> 6;
  for (int i = tid; i < 4 * NBMAX; i += 256) ((unsigned*)cnt)[i] = 0u;
  __syncthreads();
  const int chunk = (e4 + BP - 1) / BP;
  const int j0 = blockIdx.x * chunk;
  const int j1 = min(j0 + chunk, e4);
  const int4* dst4 = reinterpret_cast<const int4*>(dst);
  for (int j = j0 + tid; j < j1; j += 256) {
    int4 d = dst4[j];
    atomicAdd(&cnt[w][(unsigned)d.x >> SHIFT], 1u);
    atomicAdd(&cnt[w][(unsigned)d.y >> SHIFT], 1u);
    atomicAdd(&cnt[w][(unsigned)d.z >> SHIFT], 1u);
    atomicAdd(&cnt[w][(unsigned)d.w >> SHIFT], 1u);
  }
  if (blockIdx.x == 0) {  // tail when E%4 != 0 (same tid mapping as k_part)
    for (int t = e4 * 4 + tid; t < E; t += 256)
      atomicAdd(&cnt[w][(unsigned)dst[t] >> SHIFT], 1u);
  }
  __syncthreads();
  // layout: counts[(p*BP + b)*4 + w]
  for (int t = tid; t < NB * 4; t += 256) {
    int p = t >> 2, w2 = t & 3;
    counts[((size_t)p * BP + blockIdx.x) * 4 + w2] = cnt[w2][p];
  }
}

// ---- K2: exclusive scan of counts[NB*BP*4]; bstart[p] ----------------------
__global__ __launch_bounds__(256) void k_scan(
    unsigned* __restrict__ counts, int* __restrict__ bstart,
    int T, int NB, int E) {
  __shared__ unsigned ssum[256];
  const int tid = threadIdx.x;
  const int per = (T + 255) / 256;  // <= 64 for NB<=16
  unsigned local[64];
  unsigned sum = 0;
  for (int k = 0; k < per; ++k) {
    int idx = tid * per + k;
    unsigned v = (idx < T) ? counts[idx] : 0u;
    local[k] = sum;
    sum += v;
  }
  ssum[tid] = sum;
  __syncthreads();
  if (tid == 0) {
    unsigned acc = 0;
    for (int i = 0; i < 256; ++i) { unsigned v = ssum[i]; ssum[i] = acc; acc += v; }
  }
  __syncthreads();
  unsigned base = ssum[tid];
  for (int k = 0; k < per; ++k) {
    int idx = tid * per + k;
    if (idx < T) {
      unsigned ex = base + local[k];
      counts[idx] = ex;                       // in-place exclusive scan
      if ((idx & (BP * 4 - 1)) == 0) bstart[idx / (BP * 4)] = (int)ex;
    }
  }
  if (tid == 0) bstart[NB] = E;
}

// ---- K3: partition edges into bucket segments, per-wave cursors ------------
__global__ __launch_bounds__(256) void k_part(
    const int* __restrict__ src, const int* __restrict__ dst,
    const unsigned* __restrict__ base, unsigned* __restrict__ packed,
    int NB, int e4, int E) {
  __shared__ unsigned curw[4][NBMAX];
  const int tid = threadIdx.x, w = tid >> 6;
  for (int t = tid; t < NB * 4; t += 256) {
    int p = t >> 2, w2 = t & 3;
    curw[w2][p] = base[((size_t)p * BP + blockIdx.x) * 4 + w2];
  }
  __syncthreads();
  const int chunk = (e4 + BP - 1) / BP;
  const int j0 = blockIdx.x * chunk;
  const int j1 = min(j0 + chunk, e4);
  const int4* dst4 = reinterpret_cast<const int4*>(dst);
  const int4* src4 = reinterpret_cast<const int4*>(src);
#define PART_ONE(d, s) { unsigned p = (unsigned)(d) >> SHIFT; \
    unsigned pos = atomicAdd(&curw[w][p], 1u); \
    packed[pos] = ((unsigned)(d) & MASK) | ((unsigned)(s) << SHIFT); }
  for (int j = j0 + tid; j < j1; j += 256) {
    int4 d = dst4[j];
    int4 s = src4[j];
    PART_ONE(d.x, s.x) PART_ONE(d.y, s.y) PART_ONE(d.z, s.z) PART_ONE(d.w, s.w)
  }
  if (blockIdx.x == 0) {  // tail when E%4 != 0 (same tid mapping as k_count)
    for (int t = e4 * 4 + tid; t < E; t += 256) PART_ONE(dst[t], src[t])
  }
#undef PART_ONE
}

// ---- K4: degree from packed buckets, u16-packed bins (16 KB) ---------------
__global__ __launch_bounds__(256) void k_deg2(
    const unsigned* __restrict__ packed, const int* __restrict__ bstart,
    unsigned short* __restrict__ part16, int NP, int Kd, int N) {
  __shared__ unsigned bins[RANGE / 2];  // 16 KB
  const int tid = threadIdx.x;
  const int p = blockIdx.y, kd = blockIdx.x;
  const int lo = p * RANGE;
  const int hi = min(lo + RANGE, N);
  for (int i = tid; i < RANGE / 2; i += 256) bins[i] = 0u;
  __syncthreads();
  const int s0 = bstart[p], s1 = bstart[p + 1];
  const int chunk = (s1 - s0 + Kd - 1) / Kd;
  const int j0 = s0 + kd * chunk;
  const int j1 = min(j0 + chunk, s1);
  int j = j0 + tid;
#define DEG_ONE(v) { unsigned r = (v) & MASK; \
    atomicAdd(&bins[r >> 1], 1u << ((r & 1) * 16)); }
  for (; j + 1792 < j1; j += 2048) {
    unsigned v0 = packed[j],        v1 = packed[j + 256];
    unsigned v2 = packed[j + 512],  v3 = packed[j + 768];
    unsigned v4 = packed[j + 1024], v5 = packed[j + 1280];
    unsigned v6 = packed[j + 1536], v7 = packed[j + 1792];
    DEG_ONE(v0) DEG_ONE(v1) DEG_ONE(v2) DEG_ONE(v3)
    DEG_ONE(v4) DEG_ONE(v5) DEG_ONE(v6) DEG_ONE(v7)
  }
  for (; j < j1; j += 256) DEG_ONE(packed[j])
#undef DEG_ONE
  __syncthreads();
  // flush as u32 pairs (lo is even, rows NP-aligned)
  unsigned* my32 = (unsigned*)(part16 + (size_t)kd * NP + lo);
  const int m = (hi - lo + 1) >> 1;
  for (int i = tid; i < m; i += 256) my32[i] = bins[i];
}

// ---- K5: reduce deg partials -> dinv; dropout1 -> y ------------------------
__global__ __launch_bounds__(256) void k_node1(
    const float* __restrict__ x, const unsigned short* __restrict__ part16,
    float* __restrict__ dinv, float* __restrict__ y,
    int NP, int n, int Kd, unsigned k1a, unsigned k1b) {
  int i = blockIdx.x * blockDim.x + threadIdx.x;
  if (i >= n) return;
  unsigned d = 0;
  for (int b = 0; b < Kd; ++b) d += part16[(size_t)b * NP + i];
  float di = (d > 0) ? (1.0f / sqrtf((float)d)) : 0.0f;
  dinv[i] = di;
  unsigned o0, o1;
  threefry2x32(k1a, k1b, 0u, (unsigned)i, o0, o1);
  float u = u01_from_bits(o0 ^ o1);   // partitionable 32-bit bits = out0 ^ out1
  float xd = (u < KEEP_P) ? (x[i] / KEEP_P) : 0.0f;
  y[i] = xd * di;
}

// ---- K6/K8: binned scatter from packed bucket: bins[r] += val[s] -----------
__global__ __launch_bounds__(256) void k_scat(
    const unsigned* __restrict__ packed, const int* __restrict__ bstart,
    const float* __restrict__ val, float* __restrict__ part,
    int NP, int Ks, int N) {
  __shared__ float bins[RANGE];  // 32 KB
  const int tid = threadIdx.x;
  const int p = blockIdx.y, ks = blockIdx.x;
  const int lo = p * RANGE;
  const int hi = min(lo + RANGE, N);
  for (int i = tid; i < RANGE; i += 256) bins[i] = 0.0f;
  __syncthreads();
  const int s0 = bstart[p], s1 = bstart[p + 1];
  const int chunk = (s1 - s0 + Ks - 1) / Ks;
  const int j0 = s0 + ks * chunk;
  const int j1 = min(j0 + chunk, s1);
  int j = j0 + tid;
  for (; j + 1792 < j1; j += 2048) {
    unsigned v0 = packed[j],        v1 = packed[j + 256];
    unsigned v2 = packed[j + 512],  v3 = packed[j + 768];
    unsigned v4 = packed[j + 1024], v5 = packed[j + 1280];
    unsigned v6 = packed[j + 1536], v7 = packed[j + 1792];
    float a0 = val[v0 >> SHIFT], a1 = val[v1 >> SHIFT];
    float a2 = val[v2 >> SHIFT], a3 = val[v3 >> SHIFT];
    float a4 = val[v4 >> SHIFT], a5 = val[v5 >> SHIFT];
    float a6 = val[v6 >> SHIFT], a7 = val[v7 >> SHIFT];
    atomicAdd(&bins[v0 & MASK], a0);
    atomicAdd(&bins[v1 & MASK], a1);
    atomicAdd(&bins[v2 & MASK], a2);
    atomicAdd(&bins[v3 & MASK], a3);
    atomicAdd(&bins[v4 & MASK], a4);
    atomicAdd(&bins[v5 & MASK], a5);
    atomicAdd(&bins[v6 & MASK], a6);
    atomicAdd(&bins[v7 & MASK], a7);
  }
  for (; j < j1; j += 256) {
    unsigned v = packed[j];
    atomicAdd(&bins[v & MASK], val[v >> SHIFT]);
  }
  __syncthreads();
  float* my = part + (size_t)ks * NP;
  for (int i = tid; i < hi - lo; i += 256) my[lo + i] = bins[i];
}

// ---- K7: reduce s partials; layer1 epilogue + relu + dropout2 + W2 dot -----
__global__ __launch_bounds__(256) void k_node2(
    const float* __restrict__ part, const float* __restrict__ dinv,
    const float* __restrict__ W1, const float* __restrict__ b1,
    const float* __restrict__ W2, float* __restrict__ z2,
    int NP, int n, int Ks, unsigned k2a, unsigned k2b) {
  int i = blockIdx.x * blockDim.x + threadIdx.x;
  if (i >= n) return;
  float s = 0.0f;
  for (int b = 0; b < Ks; ++b) s += part[(size_t)b * NP + i];
  float t = s * dinv[i];
  float z = 0.0f;
  unsigned base = (unsigned)i * 16u;
#pragma unroll
  for (int c = 0; c < 16; ++c) {
    float h = W1[c] * t + b1[c];
    h = fmaxf(h, 0.0f);
    unsigned o0, o1;
    threefry2x32(k2a, k2b, 0u, base + (unsigned)c, o0, o1);
    float u = u01_from_bits(o0 ^ o1);
    float hd = (u < KEEP_P) ? (h / KEEP_P) : 0.0f;
    z += hd * W2[c];
  }
  z2[i] = z * dinv[i];   // dinv[dst] factor applied in k_final
}

// ---- K9: final combine: out = b2 + dinv * sum(partials) --------------------
__global__ __launch_bounds__(256) void k_final(
    const float* __restrict__ part, const float* __restrict__ dinv,
    const float* __restrict__ b2, float* __restrict__ out,
    int NP, int n, int Ks) {
  int i = blockIdx.x * blockDim.x + threadIdx.x;
  if (i >= n) return;
  float s = 0.0f;
  for (int b = 0; b < Ks; ++b) s += part[(size_t)b * NP + i];
  out[i] = b2[0] + dinv[i] * s;
}

extern "C" void kernel_launch(void* const* d_in, const int* in_sizes, int n_in,
                              void* d_out, int out_size, void* d_ws, size_t ws_size,
                              hipStream_t stream) {
  const float* x  = (const float*)d_in[0];
  const int* edge = (const int*)d_in[1];   // [2, E] int32
  const float* W1 = (const float*)d_in[2]; // [1,16]
  const float* b1 = (const float*)d_in[3]; // [16]
  const float* W2 = (const float*)d_in[4]; // [16,1]
  const float* b2 = (const float*)d_in[5]; // [1]
  float* out = (float*)d_out;              // [N,1] f32

  const int N = in_sizes[0];
  const int E = in_sizes[1] / 2;
  const int* src = edge;
  const int* dst = edge + E;

  const int NP = (N + 255) & ~255;
  const int NB = (N + RANGE - 1) / RANGE;   // 13 for N=100K (NB <= NBMAX)

  // ws layout: [packed E u32][counts NB*BP*4 u32][bstart NB+1]
  //            [partials: Ks*NP f32, aliased by Kd*NP u16][dinv][y][z2]
  char* w = (char*)d_ws;
  unsigned* packed = (unsigned*)w;            w += (size_t)E * 4;
  unsigned* counts = (unsigned*)w;            w += (size_t)NB * BP * 4 * 4;
  int* bstart = (int*)w;                      w += (size_t)(NB + 1) * 4;
  w = (char*)(((uintptr_t)w + 255) & ~(uintptr_t)255);
  size_t used = (size_t)(w - (char*)d_ws);
  size_t smallB = (size_t)3 * NP * 4;
  int Ks = 8;
  if (ws_size > used + smallB) {
    size_t bmax = (ws_size - used - smallB) / ((size_t)NP * 4);
    Ks = (int)(bmax < 64 ? bmax : 64);
  }
  if (Ks < 1) Ks = 1;
  int Kd = Ks * 2 <= 64 ? Ks * 2 : 64;        // u16 partials: Kd*2B <= Ks*4B
  float* part_f = (float*)w;
  unsigned short* part16 = (unsigned short*)w;  // aliased (deg phase ends first)
  float* dinv = (float*)(w + (size_t)Ks * NP * 4);
  float* y    = dinv + NP;
  float* z2   = y + NP;

  // Dropout keys: foldlike split(key(42)) under partitionable threefry.
  unsigned k1a, k1b, k2a, k2b;
  threefry2x32(0u, 42u, 0u, 0u, k1a, k1b);
  threefry2x32(0u, 42u, 0u, 1u, k2a, k2b);

  const int e4 = E >> 2;
  const int gN = (N + 255) / 256;

  k_count<<<BP, 256, 0, stream>>>(dst, counts, NB, e4, E);
  k_scan <<<1, 256, 0, stream>>>(counts, bstart, NB * BP * 4, NB, E);
  k_part <<<BP, 256, 0, stream>>>(src, dst, counts, packed, NB, e4, E);
  k_deg2 <<<dim3(Kd, NB), 256, 0, stream>>>(packed, bstart, part16, NP, Kd, N);
  k_node1<<<gN, 256, 0, stream>>>(x, part16, dinv, y, NP, N, Kd, k1a, k1b);
  k_scat <<<dim3(Ks, NB), 256, 0, stream>>>(packed, bstart, y, part_f, NP, Ks, N);
  k_node2<<<gN, 256, 0, stream>>>(part_f, dinv, W1, b1, W2, z2, NP, N, Ks, k2a, k2b);
  k_scat <<<dim3(Ks, NB), 256, 0, stream>>>(packed, bstart, z2, part_f, NP, Ks, N);
  k_final<<<gN, 256, 0, stream>>>(part_f, dinv, b2, out, NP, N, Ks);
}

// Round 8
// 231.532 us; speedup vs baseline: 4.3434x; 1.3170x over previous
//
#include <hip/hip_runtime.h>
#include <hip/hip_bf16.h>
#include <stdint.h>

// GCN forward, collapsed to scalar form (W1:[1,16], W2:[16,1] are rank-1).
// R8: fixed-capacity slot partition (no count/scan kernels, no memset) +
// small buckets (RANGE 2048) + pairwise-interleaved gather in scatters.
//   k_part: 512 blocks; block b writes edge (dst,src) into slot[b][dst>>11]
//           at an LDS-cursor position; packed u32 = (dst&2047)|(src<<11);
//           per-slot lengths to cnt[b][p]. CAP ~ 8.5 sigma over mean 256.
//   k_deg2: grid (Kd=32, NB=49): 4 KB u16-packed LDS bins over slot segs.
//   k_node1: deg partials -> dinv; dropout1 -> y.
//   k_scat:  grid (Ks=32, NB=49): 8 KB f32 bins, 16 segments per block
//            processed 2-at-a-time (independent gather chains), flush to
//            part[ks][p][2048].
//   k_node2: reduce partials; relu+dropout2+W2 dot -> z2.
//   k_scat:  layer 2. k_final: out = b2 + dinv*sum.
// No global atomics (R2-R4: gfx950 global atomic RMW is memory-side, ~20G/s,
// WRITE_SIZE=E*32B regardless of privatization/scope). Dropout reproduces
// JAX partitionable threefry (split k_i=E(key,(0,i)); bits=o0^o1 of E(k,(0,j))).
// Requires N <= 131072 (LDS cursors) and N < 2^21 (src fits 21 bits).

#define KEEP_P 0.4f
#define RANGE 2048
#define SHIFT 11
#define MASK 2047
#define BPC 512         // partition blocks
#define KS 32           // scatter slices (grid = KS x NB)
#define SEGS (BPC / KS) // 16 slot-segments per scatter block
#define NBMAX 64

__host__ __device__ inline unsigned rotl32(unsigned v, int s) {
  return (v << s) | (v >> (32 - s));
}

__host__ __device__ inline void threefry2x32(unsigned key0, unsigned key1,
                                             unsigned x0, unsigned x1,
                                             unsigned& o0, unsigned& o1) {
  unsigned ks0 = key0, ks1 = key1, ks2 = key0 ^ key1 ^ 0x1BD11BDAu;
  unsigned v0 = x0 + ks0, v1 = x1 + ks1;
#define TF_R(r) { v0 += v1; v1 = rotl32(v1, r); v1 ^= v0; }
  TF_R(13) TF_R(15) TF_R(26) TF_R(6)
  v0 += ks1; v1 += ks2 + 1u;
  TF_R(17) TF_R(29) TF_R(16) TF_R(24)
  v0 += ks2; v1 += ks0 + 2u;
  TF_R(13) TF_R(15) TF_R(26) TF_R(6)
  v0 += ks0; v1 += ks1 + 3u;
  TF_R(17) TF_R(29) TF_R(16) TF_R(24)
  v0 += ks1; v1 += ks2 + 4u;
  TF_R(13) TF_R(15) TF_R(26) TF_R(6)
  v0 += ks2; v1 += ks0 + 5u;
#undef TF_R
  o0 = v0; o1 = v1;
}

__device__ inline float u01_from_bits(unsigned bits) {
  return __uint_as_float((bits >> 9) | 0x3f800000u) - 1.0f;
}

// ---- K1: slot partition, per-block LDS cursors -----------------------------
__global__ __launch_bounds__(256) void k_part(
    const int* __restrict__ src, const int* __restrict__ dst,
    unsigned* __restrict__ slots, unsigned* __restrict__ cnt,
    int NB, int CAP, int e4, int E) {
  __shared__ unsigned cur[NBMAX];
  const int tid = threadIdx.x;
  const size_t blkbase = (size_t)blockIdx.x * NB;
  for (int p = tid; p < NB; p += 256) cur[p] = (unsigned)(p * CAP);
  __syncthreads();
  const int chunk = (e4 + BPC - 1) / BPC;
  const int j0 = blockIdx.x * chunk;
  const int j1 = min(j0 + chunk, e4);
  const int4* dst4 = reinterpret_cast<const int4*>(dst);
  const int4* src4 = reinterpret_cast<const int4*>(src);
  unsigned* myslots = slots + blkbase * CAP;
#define PART_ONE(d, s) { unsigned p = (unsigned)(d) >> SHIFT; \
    unsigned pos = atomicAdd(&cur[p], 1u); \
    myslots[pos] = ((unsigned)(d) & MASK) | ((unsigned)(s) << SHIFT); }
  for (int j = j0 + tid; j < j1; j += 256) {
    int4 d = dst4[j];
    int4 s = src4[j];
    PART_ONE(d.x, s.x) PART_ONE(d.y, s.y) PART_ONE(d.z, s.z) PART_ONE(d.w, s.w)
  }
  if (blockIdx.x == 0) {  // tail when E%4 != 0 (dead for E=6.4M)
    for (int t = e4 * 4 + tid; t < E; t += 256) PART_ONE(dst[t], src[t])
  }
#undef PART_ONE
  __syncthreads();
  for (int p = tid; p < NB; p += 256)
    cnt[blkbase + p] = cur[p] - (unsigned)(p * CAP);
}

// ---- K2: degree from slots, u16-packed bins (4 KB) -------------------------
__global__ __launch_bounds__(256) void k_deg2(
    const unsigned* __restrict__ slots, const unsigned* __restrict__ cnt,
    unsigned short* __restrict__ part16, int NB, int CAP) {
  __shared__ unsigned bins[RANGE / 2];  // 4 KB
  const int tid = threadIdx.x;
  const int p = blockIdx.y, kd = blockIdx.x;
  for (int i = tid; i < RANGE / 2; i += 256) bins[i] = 0u;
  __syncthreads();
  const int b0 = kd * SEGS;
#define DEG_ONE(v) { unsigned r = (v) & MASK; \
    atomicAdd(&bins[r >> 1], 1u << ((r & 1) * 16)); }
  for (int u = 0; u < SEGS / 2; ++u) {
    const int bA = b0 + u, bB = b0 + u + SEGS / 2;
    const int lA = cnt[(size_t)bA * NB + p];
    const int lB = cnt[(size_t)bB * NB + p];
    const unsigned* eA = slots + ((size_t)bA * NB + p) * CAP;
    const unsigned* eB = slots + ((size_t)bB * NB + p) * CAP;
    int jA = tid, jB = tid;
    while (jA < lA && jB < lB) {
      unsigned vA = eA[jA], vB = eB[jB];
      DEG_ONE(vA) DEG_ONE(vB)
      jA += 256; jB += 256;
    }
    for (; jA < lA; jA += 256) DEG_ONE(eA[jA])
    for (; jB < lB; jB += 256) DEG_ONE(eB[jB])
  }
#undef DEG_ONE
  __syncthreads();
  unsigned* my32 = (unsigned*)(part16 + ((size_t)kd * gridDim.y + p) * RANGE);
  for (int i = tid; i < RANGE / 2; i += 256) my32[i] = bins[i];
}

// ---- K3: reduce deg partials -> dinv; dropout1 -> y ------------------------
__global__ __launch_bounds__(256) void k_node1(
    const float* __restrict__ x, const unsigned short* __restrict__ part16,
    float* __restrict__ dinv, float* __restrict__ y,
    int NB, int n, unsigned k1a, unsigned k1b) {
  int i = blockIdx.x * blockDim.x + threadIdx.x;
  if (i >= n) return;
  const int p = i >> SHIFT, r = i & MASK;
  unsigned d = 0;
  for (int b = 0; b < KS; ++b)
    d += part16[((size_t)b * NB + p) * RANGE + r];
  float di = (d > 0) ? (1.0f / sqrtf((float)d)) : 0.0f;
  dinv[i] = di;
  unsigned o0, o1;
  threefry2x32(k1a, k1b, 0u, (unsigned)i, o0, o1);
  float u = u01_from_bits(o0 ^ o1);   // partitionable 32-bit bits = out0 ^ out1
  float xd = (u < KEEP_P) ? (x[i] / KEEP_P) : 0.0f;
  y[i] = xd * di;
}

// ---- K4/K6: binned scatter from slots: bins[r] += val[s] -------------------
__global__ __launch_bounds__(256) void k_scat(
    const unsigned* __restrict__ slots, const unsigned* __restrict__ cnt,
    const float* __restrict__ val, float* __restrict__ part,
    int NB, int CAP) {
  __shared__ float bins[RANGE];  // 8 KB
  const int tid = threadIdx.x;
  const int p = blockIdx.y, ks = blockIdx.x;
  for (int i = tid; i < RANGE; i += 256) bins[i] = 0.0f;
  __syncthreads();
  const int b0 = ks * SEGS;
  for (int u = 0; u < SEGS / 2; ++u) {
    const int bA = b0 + u, bB = b0 + u + SEGS / 2;
    const int lA = cnt[(size_t)bA * NB + p];
    const int lB = cnt[(size_t)bB * NB + p];
    const unsigned* eA = slots + ((size_t)bA * NB + p) * CAP;
    const unsigned* eB = slots + ((size_t)bB * NB + p) * CAP;
    int jA = tid, jB = tid;
    while (jA < lA && jB < lB) {
      unsigned vA = eA[jA], vB = eB[jB];
      float aA = val[vA >> SHIFT], aB = val[vB >> SHIFT];
      atomicAdd(&bins[vA & MASK], aA);
      atomicAdd(&bins[vB & MASK], aB);
      jA += 256; jB += 256;
    }
    for (; jA < lA; jA += 256) {
      unsigned v = eA[jA];
      atomicAdd(&bins[v & MASK], val[v >> SHIFT]);
    }
    for (; jB < lB; jB += 256) {
      unsigned v = eB[jB];
      atomicAdd(&bins[v & MASK], val[v >> SHIFT]);
    }
  }
  __syncthreads();
  float* my = part + ((size_t)ks * NB + p) * RANGE;
  for (int i = tid; i < RANGE; i += 256) my[i] = bins[i];
}

// ---- K5: reduce s partials; layer1 epilogue + relu + dropout2 + W2 dot -----
__global__ __launch_bounds__(256) void k_node2(
    const float* __restrict__ part, const float* __restrict__ dinv,
    const float* __restrict__ W1, const float* __restrict__ b1,
    const float* __restrict__ W2, float* __restrict__ z2,
    int NB, int n, unsigned k2a, unsigned k2b) {
  int i = blockIdx.x * blockDim.x + threadIdx.x;
  if (i >= n) return;
  const int p = i >> SHIFT, r = i & MASK;
  float s = 0.0f;
  for (int b = 0; b < KS; ++b)
    s += part[((size_t)b * NB + p) * RANGE + r];
  float t = s * dinv[i];
  float z = 0.0f;
  unsigned base = (unsigned)i * 16u;
#pragma unroll
  for (int c = 0; c < 16; ++c) {
    float h = W1[c] * t + b1[c];
    h = fmaxf(h, 0.0f);
    unsigned o0, o1;
    threefry2x32(k2a, k2b, 0u, base + (unsigned)c, o0, o1);
    float u = u01_from_bits(o0 ^ o1);
    float hd = (u < KEEP_P) ? (h / KEEP_P) : 0.0f;
    z += hd * W2[c];
  }
  z2[i] = z * dinv[i];   // dinv[dst] factor applied in k_final
}

// ---- K7: final combine: out = b2 + dinv * sum(partials) --------------------
__global__ __launch_bounds__(256) void k_final(
    const float* __restrict__ part, const float* __restrict__ dinv,
    const float* __restrict__ b2, float* __restrict__ out,
    int NB, int n) {
  int i = blockIdx.x * blockDim.x + threadIdx.x;
  if (i >= n) return;
  const int p = i >> SHIFT, r = i & MASK;
  float s = 0.0f;
  for (int b = 0; b < KS; ++b)
    s += part[((size_t)b * NB + p) * RANGE + r];
  out[i] = b2[0] + dinv[i] * s;
}

extern "C" void kernel_launch(void* const* d_in, const int* in_sizes, int n_in,
                              void* d_out, int out_size, void* d_ws, size_t ws_size,
                              hipStream_t stream) {
  const float* x  = (const float*)d_in[0];
  const int* edge = (const int*)d_in[1];   // [2, E] int32
  const float* W1 = (const float*)d_in[2]; // [1,16]
  const float* b1 = (const float*)d_in[3]; // [16]
  const float* W2 = (const float*)d_in[4]; // [16,1]
  const float* b2 = (const float*)d_in[5]; // [1]
  float* out = (float*)d_out;              // [N,1] f32

  const int N = in_sizes[0];
  const int E = in_sizes[1] / 2;
  const int* src = edge;
  const int* dst = edge + E;

  const int NP = (N + 255) & ~255;
  const int NB = (N + RANGE - 1) / RANGE;   // 49 for N=100K (<= NBMAX)

  // ws layout: [slots NB*BPC*CAP u32][cnt BPC*NB u32]
  //            [part KS*NB*RANGE f32 (aliases deg u16 partials)][dinv][y][z2]
  const size_t cnt_sz  = (size_t)BPC * NB * 4;
  const size_t part_sz = (size_t)KS * NB * RANGE * 4;
  const size_t small_sz = (size_t)3 * NP * 4;
  size_t fixed = cnt_sz + part_sz + small_sz + 512;
  size_t avail = ws_size > fixed ? ws_size - fixed : 0;
  int CAP = (int)(avail / ((size_t)NB * BPC * 4));
  if (CAP > 512) CAP = 512;   // 16+ sigma, plenty
  if (CAP < 288) CAP = 288;   // ws guard (mean 256; should not trigger)

  char* w = (char*)d_ws;
  unsigned* slots = (unsigned*)w;        w += (size_t)NB * BPC * CAP * 4;
  unsigned* cnt   = (unsigned*)w;        w += cnt_sz;
  w = (char*)(((uintptr_t)w + 255) & ~(uintptr_t)255);
  float* part_f = (float*)w;
  unsigned short* part16 = (unsigned short*)w;  // aliased (deg phase ends first)
  w += part_sz;
  float* dinv = (float*)w;
  float* y    = dinv + NP;
  float* z2   = y + NP;

  // Dropout keys: foldlike split(key(42)) under partitionable threefry.
  unsigned k1a, k1b, k2a, k2b;
  threefry2x32(0u, 42u, 0u, 0u, k1a, k1b);
  threefry2x32(0u, 42u, 0u, 1u, k2a, k2b);

  const int e4 = E >> 2;
  const int gN = (N + 255) / 256;

  k_part <<<BPC, 256, 0, stream>>>(src, dst, slots, cnt, NB, CAP, e4, E);
  k_deg2 <<<dim3(KS, NB), 256, 0, stream>>>(slots, cnt, part16, NB, CAP);
  k_node1<<<gN, 256, 0, stream>>>(x, part16, dinv, y, NB, N, k1a, k1b);
  k_scat <<<dim3(KS, NB), 256, 0, stream>>>(slots, cnt, y, part_f, NB, CAP);
  k_node2<<<gN, 256, 0, stream>>>(part_f, dinv, W1, b1, W2, z2, NB, N, k2a, k2b);
  k_scat <<<dim3(KS, NB), 256, 0, stream>>>(slots, cnt, z2, part_f, NB, CAP);
  k_final<<<gN, 256, 0, stream>>>(part_f, dinv, b2, out, NB, N);
}

// Round 9
// 225.725 us; speedup vs baseline: 4.4551x; 1.0257x over previous
//
#include <hip/hip_runtime.h>
#include <hip/hip_bf16.h>
#include <stdint.h>

// GCN forward, collapsed to scalar form (W1:[1,16], W2:[16,1] are rank-1).
// R9 (on R8's fixed-capacity slot partition):
//  - k_part: LDS tile-sort staging. R8 stored each edge with a 4B random
//    write at an LDS-cursor position; per-block slot working set (76 KB x 64
//    blocks/XCD) thrashed L2 with partial lines. Now each 2048-edge tile is
//    counted, scanned, staged sorted-by-bucket in LDS, then written out as
//    bucket-contiguous runs (~168 B) at per-block cursors.
//  - k_scat/k_deg2: wave-per-segment, uint4 slot loads, 2 segments in
//    flight -> 8 independent val[] gathers per lane (R8 had 2; Occ 25->47%
//    did nothing, so the wall was per-thread MLP, not wave count).
// No global atomics (R2-R4: gfx950 global atomic RMW is memory-side, ~20G/s,
// WRITE_SIZE=E*32B regardless of privatization/scope). Dropout reproduces
// JAX partitionable threefry (split k_i=E(key,(0,i)); bits=o0^o1 of E(k,(0,j))).
// Requires N <= 131072 (NBMAX) and N < 2^21 (src fits 21 bits).

#define KEEP_P 0.4f
#define RANGE 2048
#define SHIFT 11
#define MASK 2047
#define BPC 512         // partition blocks
#define KS 32           // scatter slices (grid = KS x NB)
#define SEGS (BPC / KS) // 16 slot-segments per scatter block
#define NBMAX 64
#define TILE 2048       // edges per k_part tile
#define TILE4 (TILE / 4)

__host__ __device__ inline unsigned rotl32(unsigned v, int s) {
  return (v << s) | (v >> (32 - s));
}

__host__ __device__ inline void threefry2x32(unsigned key0, unsigned key1,
                                             unsigned x0, unsigned x1,
                                             unsigned& o0, unsigned& o1) {
  unsigned ks0 = key0, ks1 = key1, ks2 = key0 ^ key1 ^ 0x1BD11BDAu;
  unsigned v0 = x0 + ks0, v1 = x1 + ks1;
#define TF_R(r) { v0 += v1; v1 = rotl32(v1, r); v1 ^= v0; }
  TF_R(13) TF_R(15) TF_R(26) TF_R(6)
  v0 += ks1; v1 += ks2 + 1u;
  TF_R(17) TF_R(29) TF_R(16) TF_R(24)
  v0 += ks2; v1 += ks0 + 2u;
  TF_R(13) TF_R(15) TF_R(26) TF_R(6)
  v0 += ks0; v1 += ks1 + 3u;
  TF_R(17) TF_R(29) TF_R(16) TF_R(24)
  v0 += ks1; v1 += ks2 + 4u;
  TF_R(13) TF_R(15) TF_R(26) TF_R(6)
  v0 += ks2; v1 += ks0 + 5u;
#undef TF_R
  o0 = v0; o1 = v1;
}

__device__ inline float u01_from_bits(unsigned bits) {
  return __uint_as_float((bits >> 9) | 0x3f800000u) - 1.0f;
}

// ---- K1: slot partition with LDS tile-sort staging -------------------------
__global__ __launch_bounds__(256) void k_part(
    const int* __restrict__ src, const int* __restrict__ dst,
    unsigned* __restrict__ slots, unsigned* __restrict__ cnt,
    int NB, int CAP, int e4, int E) {
  __shared__ unsigned hist[NBMAX], scan_s[NBMAX + 1], off[NBMAX];
  __shared__ unsigned tbase[NBMAX], cur[NBMAX];
  __shared__ unsigned stage[TILE];
  __shared__ unsigned char stage_p[TILE];
  const int tid = threadIdx.x;
  const size_t blkbase = (size_t)blockIdx.x * NB;
  unsigned* myslots = slots + blkbase * CAP;
  for (int p = tid; p < NB; p += 256) cur[p] = (unsigned)(p * CAP);
  const int chunk = (e4 + BPC - 1) / BPC;
  const int j0 = blockIdx.x * chunk;
  const int j1 = min(j0 + chunk, e4);
  const int4* dst4 = reinterpret_cast<const int4*>(dst);
  const int4* src4 = reinterpret_cast<const int4*>(src);

  for (int t0 = j0; t0 < j1; t0 += TILE4) {
    __syncthreads();
    for (int p = tid; p < NB; p += 256) hist[p] = 0u;
    __syncthreads();
    // A: count this tile (hold dst in regs)
    const int ja = t0 + tid, jb = t0 + TILE4 / 2 + tid;
    const bool va = ja < j1 && tid < TILE4 / 2;
    const bool vb = jb < j1;
    int4 da, db;
    if (va) {
      da = dst4[ja];
      atomicAdd(&hist[(unsigned)da.x >> SHIFT], 1u);
      atomicAdd(&hist[(unsigned)da.y >> SHIFT], 1u);
      atomicAdd(&hist[(unsigned)da.z >> SHIFT], 1u);
      atomicAdd(&hist[(unsigned)da.w >> SHIFT], 1u);
    }
    if (vb) {
      db = dst4[jb];
      atomicAdd(&hist[(unsigned)db.x >> SHIFT], 1u);
      atomicAdd(&hist[(unsigned)db.y >> SHIFT], 1u);
      atomicAdd(&hist[(unsigned)db.z >> SHIFT], 1u);
      atomicAdd(&hist[(unsigned)db.w >> SHIFT], 1u);
    }
    __syncthreads();
    // B: scan
    if (tid == 0) {
      unsigned acc = 0;
      for (int p = 0; p < NB; ++p) { scan_s[p] = acc; acc += hist[p]; }
      scan_s[NB] = acc;
    }
    __syncthreads();
    for (int p = tid; p < NB; p += 256) {
      off[p] = scan_s[p];
      tbase[p] = cur[p];
      cur[p] += hist[p];
    }
    __syncthreads();
    // C: stage sorted-by-bucket
#define STAGE1(d, s) { unsigned ud = (unsigned)(d), us = (unsigned)(s); \
    unsigned p = ud >> SHIFT; unsigned pos = atomicAdd(&off[p], 1u); \
    stage[pos] = (ud & MASK) | (us << SHIFT); stage_p[pos] = (unsigned char)p; }
    if (va) {
      int4 sa = src4[ja];
      STAGE1(da.x, sa.x) STAGE1(da.y, sa.y) STAGE1(da.z, sa.z) STAGE1(da.w, sa.w)
    }
    if (vb) {
      int4 sb = src4[jb];
      STAGE1(db.x, sb.x) STAGE1(db.y, sb.y) STAGE1(db.z, sb.z) STAGE1(db.w, sb.w)
    }
#undef STAGE1
    __syncthreads();
    // D: write out bucket-contiguous runs
    const int tc = (int)scan_s[NB];
    for (int i = tid; i < tc; i += 256) {
      unsigned p = stage_p[i];
      myslots[tbase[p] + ((unsigned)i - scan_s[p])] = stage[i];
    }
  }
  __syncthreads();
  if (blockIdx.x == 0) {  // tail when E%4 != 0 (dead for E=6.4M)
    for (int t = e4 * 4 + tid; t < E; t += 256) {
      unsigned ud = (unsigned)dst[t], us = (unsigned)src[t];
      unsigned p = ud >> SHIFT;
      unsigned pos = atomicAdd(&cur[p], 1u);
      myslots[pos] = (ud & MASK) | (us << SHIFT);
    }
  }
  __syncthreads();
  for (int p = tid; p < NB; p += 256)
    cnt[blkbase + p] = cur[p] - (unsigned)(p * CAP);
}

// ---- K2: degree from slots, wave-per-segment, uint4 loads ------------------
__global__ __launch_bounds__(256) void k_deg2(
    const unsigned* __restrict__ slots, const unsigned* __restrict__ cnt,
    unsigned short* __restrict__ part16, int NB, int CAP) {
  __shared__ unsigned bins[RANGE / 2];  // 4 KB, u16-packed
  const int tid = threadIdx.x, w = tid >> 6, lane = tid & 63;
  const int p = blockIdx.y, kd = blockIdx.x;
  for (int i = tid; i < RANGE / 2; i += 256) bins[i] = 0u;
  __syncthreads();
  const int b0 = kd * SEGS;
#define DEG_ONE(v) { unsigned r = (v) & MASK; \
    atomicAdd(&bins[r >> 1], 1u << ((r & 1) * 16)); }
  for (int q = 0; q < 4; q += 2) {
    const int bA = b0 + w + 4 * q, bB = b0 + w + 4 * (q + 1);
    const int lA = cnt[(size_t)bA * NB + p];
    const int lB = cnt[(size_t)bB * NB + p];
    const unsigned* eA = slots + ((size_t)bA * NB + p) * CAP;
    const unsigned* eB = slots + ((size_t)bB * NB + p) * CAP;
    const int lmax = lA > lB ? lA : lB;
    for (int base = 4 * lane; base < lmax; base += 256) {
      if (base + 4 <= lA) {
        uint4 av = *reinterpret_cast<const uint4*>(eA + base);
        DEG_ONE(av.x) DEG_ONE(av.y) DEG_ONE(av.z) DEG_ONE(av.w)
      } else {
        for (int k = base; k < lA; ++k) DEG_ONE(eA[k])
      }
      if (base + 4 <= lB) {
        uint4 bv = *reinterpret_cast<const uint4*>(eB + base);
        DEG_ONE(bv.x) DEG_ONE(bv.y) DEG_ONE(bv.z) DEG_ONE(bv.w)
      } else {
        for (int k = base; k < lB; ++k) DEG_ONE(eB[k])
      }
    }
  }
#undef DEG_ONE
  __syncthreads();
  unsigned* my32 = (unsigned*)(part16 + ((size_t)kd * gridDim.y + p) * RANGE);
  for (int i = tid; i < RANGE / 2; i += 256) my32[i] = bins[i];
}

// ---- K3: reduce deg partials -> dinv; dropout1 -> y ------------------------
__global__ __launch_bounds__(256) void k_node1(
    const float* __restrict__ x, const unsigned short* __restrict__ part16,
    float* __restrict__ dinv, float* __restrict__ y,
    int NB, int n, unsigned k1a, unsigned k1b) {
  int i = blockIdx.x * blockDim.x + threadIdx.x;
  if (i >= n) return;
  const int p = i >> SHIFT, r = i & MASK;
  unsigned d = 0;
  for (int b = 0; b < KS; ++b)
    d += part16[((size_t)b * NB + p) * RANGE + r];
  float di = (d > 0) ? (1.0f / sqrtf((float)d)) : 0.0f;
  dinv[i] = di;
  unsigned o0, o1;
  threefry2x32(k1a, k1b, 0u, (unsigned)i, o0, o1);
  float u = u01_from_bits(o0 ^ o1);   // partitionable 32-bit bits = out0 ^ out1
  float xd = (u < KEEP_P) ? (x[i] / KEEP_P) : 0.0f;
  y[i] = xd * di;
}

// ---- K4/K6: binned scatter, wave-per-segment, uint4 + 8-deep gathers -------
__global__ __launch_bounds__(256) void k_scat(
    const unsigned* __restrict__ slots, const unsigned* __restrict__ cnt,
    const float* __restrict__ val, float* __restrict__ part,
    int NB, int CAP) {
  __shared__ float bins[RANGE];  // 8 KB
  const int tid = threadIdx.x, w = tid >> 6, lane = tid & 63;
  const int p = blockIdx.y, ks = blockIdx.x;
  for (int i = tid; i < RANGE; i += 256) bins[i] = 0.0f;
  __syncthreads();
  const int b0 = ks * SEGS;
  for (int q = 0; q < 4; q += 2) {
    const int bA = b0 + w + 4 * q, bB = b0 + w + 4 * (q + 1);
    const int lA = cnt[(size_t)bA * NB + p];
    const int lB = cnt[(size_t)bB * NB + p];
    const unsigned* eA = slots + ((size_t)bA * NB + p) * CAP;
    const unsigned* eB = slots + ((size_t)bB * NB + p) * CAP;
    const int lmax = lA > lB ? lA : lB;
    for (int base = 4 * lane; base < lmax; base += 256) {
      const bool fA = base + 4 <= lA, fB = base + 4 <= lB;
      if (fA && fB) {
        uint4 av = *reinterpret_cast<const uint4*>(eA + base);
        uint4 bv = *reinterpret_cast<const uint4*>(eB + base);
        float a0 = val[av.x >> SHIFT], a1 = val[av.y >> SHIFT];
        float a2 = val[av.z >> SHIFT], a3 = val[av.w >> SHIFT];
        float c0 = val[bv.x >> SHIFT], c1 = val[bv.y >> SHIFT];
        float c2 = val[bv.z >> SHIFT], c3 = val[bv.w >> SHIFT];
        atomicAdd(&bins[av.x & MASK], a0);
        atomicAdd(&bins[av.y & MASK], a1);
        atomicAdd(&bins[av.z & MASK], a2);
        atomicAdd(&bins[av.w & MASK], a3);
        atomicAdd(&bins[bv.x & MASK], c0);
        atomicAdd(&bins[bv.y & MASK], c1);
        atomicAdd(&bins[bv.z & MASK], c2);
        atomicAdd(&bins[bv.w & MASK], c3);
      } else {
        if (fA) {
          uint4 av = *reinterpret_cast<const uint4*>(eA + base);
          float a0 = val[av.x >> SHIFT], a1 = val[av.y >> SHIFT];
          float a2 = val[av.z >> SHIFT], a3 = val[av.w >> SHIFT];
          atomicAdd(&bins[av.x & MASK], a0);
          atomicAdd(&bins[av.y & MASK], a1);
          atomicAdd(&bins[av.z & MASK], a2);
          atomicAdd(&bins[av.w & MASK], a3);
        } else {
          for (int k = base; k < lA; ++k) {
            unsigned v = eA[k];
            atomicAdd(&bins[v & MASK], val[v >> SHIFT]);
          }
        }
        if (fB) {
          uint4 bv = *reinterpret_cast<const uint4*>(eB + base);
          float c0 = val[bv.x >> SHIFT], c1 = val[bv.y >> SHIFT];
          float c2 = val[bv.z >> SHIFT], c3 = val[bv.w >> SHIFT];
          atomicAdd(&bins[bv.x & MASK], c0);
          atomicAdd(&bins[bv.y & MASK], c1);
          atomicAdd(&bins[bv.z & MASK], c2);
          atomicAdd(&bins[bv.w & MASK], c3);
        } else {
          for (int k = base; k < lB; ++k) {
            unsigned v = eB[k];
            atomicAdd(&bins[v & MASK], val[v >> SHIFT]);
          }
        }
      }
    }
  }
  __syncthreads();
  float* my = part + ((size_t)ks * NB + p) * RANGE;
  for (int i = tid; i < RANGE; i += 256) my[i] = bins[i];
}

// ---- K5: reduce s partials; layer1 epilogue + relu + dropout2 + W2 dot -----
__global__ __launch_bounds__(256) void k_node2(
    const float* __restrict__ part, const float* __restrict__ dinv,
    const float* __restrict__ W1, const float* __restrict__ b1,
    const float* __restrict__ W2, float* __restrict__ z2,
    int NB, int n, unsigned k2a, unsigned k2b) {
  int i = blockIdx.x * blockDim.x + threadIdx.x;
  if (i >= n) return;
  const int p = i >> SHIFT, r = i & MASK;
  float s = 0.0f;
  for (int b = 0; b < KS; ++b)
    s += part[((size_t)b * NB + p) * RANGE + r];
  float t = s * dinv[i];
  float z = 0.0f;
  unsigned base = (unsigned)i * 16u;
#pragma unroll
  for (int c = 0; c < 16; ++c) {
    float h = W1[c] * t + b1[c];
    h = fmaxf(h, 0.0f);
    unsigned o0, o1;
    threefry2x32(k2a, k2b, 0u, base + (unsigned)c, o0, o1);
    float u = u01_from_bits(o0 ^ o1);
    float hd = (u < KEEP_P) ? (h / KEEP_P) : 0.0f;
    z += hd * W2[c];
  }
  z2[i] = z * dinv[i];   // dinv[dst] factor applied in k_final
}

// ---- K7: final combine: out = b2 + dinv * sum(partials) --------------------
__global__ __launch_bounds__(256) void k_final(
    const float* __restrict__ part, const float* __restrict__ dinv,
    const float* __restrict__ b2, float* __restrict__ out,
    int NB, int n) {
  int i = blockIdx.x * blockDim.x + threadIdx.x;
  if (i >= n) return;
  const int p = i >> SHIFT, r = i & MASK;
  float s = 0.0f;
  for (int b = 0; b < KS; ++b)
    s += part[((size_t)b * NB + p) * RANGE + r];
  out[i] = b2[0] + dinv[i] * s;
}

extern "C" void kernel_launch(void* const* d_in, const int* in_sizes, int n_in,
                              void* d_out, int out_size, void* d_ws, size_t ws_size,
                              hipStream_t stream) {
  const float* x  = (const float*)d_in[0];
  const int* edge = (const int*)d_in[1];   // [2, E] int32
  const float* W1 = (const float*)d_in[2]; // [1,16]
  const float* b1 = (const float*)d_in[3]; // [16]
  const float* W2 = (const float*)d_in[4]; // [16,1]
  const float* b2 = (const float*)d_in[5]; // [1]
  float* out = (float*)d_out;              // [N,1] f32

  const int N = in_sizes[0];
  const int E = in_sizes[1] / 2;
  const int* src = edge;
  const int* dst = edge + E;

  const int NP = (N + 255) & ~255;
  const int NB = (N + RANGE - 1) / RANGE;   // 49 for N=100K (<= NBMAX)

  // ws layout: [slots NB*BPC*CAP u32][cnt BPC*NB u32]
  //            [part KS*NB*RANGE f32 (aliases deg u16 partials)][dinv][y][z2]
  const size_t cnt_sz  = (size_t)BPC * NB * 4;
  const size_t part_sz = (size_t)KS * NB * RANGE * 4;
  const size_t small_sz = (size_t)3 * NP * 4;
  size_t fixed = cnt_sz + part_sz + small_sz + 512;
  size_t avail = ws_size > fixed ? ws_size - fixed : 0;
  int CAP = (int)(avail / ((size_t)NB * BPC * 4));
  CAP &= ~3;                  // 16B-aligned slot starts for uint4 loads
  if (CAP > 512) CAP = 512;   // 16+ sigma over mean 256, plenty
  if (CAP < 288) CAP = 288;   // ws guard (should not trigger)

  char* w = (char*)d_ws;
  unsigned* slots = (unsigned*)w;        w += (size_t)NB * BPC * CAP * 4;
  unsigned* cnt   = (unsigned*)w;        w += cnt_sz;
  w = (char*)(((uintptr_t)w + 255) & ~(uintptr_t)255);
  float* part_f = (float*)w;
  unsigned short* part16 = (unsigned short*)w;  // aliased (deg phase ends first)
  w += part_sz;
  float* dinv = (float*)w;
  float* y    = dinv + NP;
  float* z2   = y + NP;

  // Dropout keys: foldlike split(key(42)) under partitionable threefry.
  unsigned k1a, k1b, k2a, k2b;
  threefry2x32(0u, 42u, 0u, 0u, k1a, k1b);
  threefry2x32(0u, 42u, 0u, 1u, k2a, k2b);

  const int e4 = E >> 2;
  const int gN = (N + 255) / 256;

  k_part <<<BPC, 256, 0, stream>>>(src, dst, slots, cnt, NB, CAP, e4, E);
  k_deg2 <<<dim3(KS, NB), 256, 0, stream>>>(slots, cnt, part16, NB, CAP);
  k_node1<<<gN, 256, 0, stream>>>(x, part16, dinv, y, NB, N, k1a, k1b);
  k_scat <<<dim3(KS, NB), 256, 0, stream>>>(slots, cnt, y, part_f, NB, CAP);
  k_node2<<<gN, 256, 0, stream>>>(part_f, dinv, W1, b1, W2, z2, NB, N, k2a, k2b);
  k_scat <<<dim3(KS, NB), 256, 0, stream>>>(slots, cnt, z2, part_f, NB, CAP);
  k_final<<<gN, 256, 0, stream>>>(part_f, dinv, b2, out, NB, N);
}